// Round 8
// baseline (1129.594 us; speedup 1.0000x reference)
//
#include <hip/hip_runtime.h>
#include <math.h>

#define NNODES  200000
#define NEDGES  6400000
#define NGRAPHS 512
#define FIN     92
#define WID     10
#define HPAD    16                     // hs row padded to 16 floats (64 B)
#define NBLK    ((NNODES + 255) / 256) // 782

// partition geometry (round-12 scatter kept as-is)
#define LBITS   10
#define LSIZE   1024                   // coarse bucket (both planes)
#define LMASK   (LSIZE - 1)
#define NB      196                    // coarse buckets
#define SUBSH   7
#define SUBN    128                    // dst nodes per sub-bucket
#define NSUB    1563                   // ceil(200000/128) dst sub-buckets
#define NSUBP   1608                   // padded alloc (incl sentinel)
#define PBLK    1280                   // partition blocks (5/CU exact)
#define EPB     (NEDGES / PBLK)        // 5000 edges per partition block (exact)
#define TILE    1250                   // staging tile (EPB = 4 * TILE exactly)
#define NTILE   (EPB / TILE)           // 4
#define CELLS   (2 * NB)               // 392 (dst plane + src plane)
#define CNT_N   (CELLS * PBLK)         // 501,760 scan elements
#define SBLKS   (CNT_N / 256)          // 1960 scan blocks (exact)
#define REF_GRID (NB * 8)              // 1568 refine blocks (8 per parent)

// chunk-ordered rows (kept: csr sorted by (local, srcChunk))
#define CHBITS  14
#define NCHK    13                     // ceil(200000/16384) src chunks
#define SKEYS   (SUBN * NCHK)          // 1664 keys per sub-bucket
#define SKPAD   1792                   // 256*7 padded key array
#define SKPT    7                      // keys per thread in scan
#define SMAX    5120                   // LDS staging cap: mean 4096 + 16 sigma

// round-15: agg1 = 8 lanes/node, ONE counted loop, ZERO barriers.
// Round-7 verdict: the global phase lock saves ~180 MB (FETCH 244 vs 423)
// but pays ~2x in tail latency (1.67 TB/s, VALU 3.8%) -> straggler-bound.
// Round-4/5's unsynchronized 8-lane ran 423 MB @ 3.2 TB/s; rounds 6->7
// measured the break-chain removal worth 25-45 us. This version = r4
// structure + counted loop (no chunk logic, no breaks): 4 independent
// gather iterations per lane pipeline freely.
#define LPN     8
#define LPNSH   3
#define NPB     (256 / LPN)            // 32 nodes per block
#define AGG_BLKS (NNODES / NPB)        // 6250 (exact)

// ---------------------------------------------------------------------------
// P1: per-(bucket,block) counts via LDS histograms; dst histogrammed at
// sub-bucket granularity then summed 8-way (cnt values = coarse), sub totals
// accumulated into global subcnt. ZERO hot-path atomics.
// ---------------------------------------------------------------------------
__global__ void k_part_count(const int* __restrict__ src,
                             const int* __restrict__ dst,
                             int* __restrict__ cnt,
                             int* __restrict__ subcnt) {
    __shared__ int hSub[NSUB];
    __shared__ int hS[NB];
    int tid = threadIdx.x, k = blockIdx.x;
    for (int i = tid; i < NSUB; i += 256) hSub[i] = 0;
    if (tid < NB) hS[tid] = 0;
    __syncthreads();
    int base = k * EPB;
    for (int i = tid; i < EPB; i += 256) {
        int e = base + i;
        atomicAdd(&hSub[dst[e] >> SUBSH], 1);
        atomicAdd(&hS[src[e] >> LBITS], 1);
    }
    __syncthreads();
    if (tid < NB) {
        int s = 0;
        int b0 = tid * 8;
#pragma unroll
        for (int j = 0; j < 8; j++) {
            int ix = b0 + j;
            if (ix < NSUB) s += hSub[ix];
        }
        cnt[tid * PBLK + k] = s;
        cnt[(NB + tid) * PBLK + k] = hS[tid];
    }
    for (int i = tid; i < NSUB; i += 256) {
        int v = hSub[i];
        if (v) atomicAdd(&subcnt[i], v);
    }
}

// ---------------------------------------------------------------------------
// Scan step 1: per-block (256-elem) partial sums of cnt
// ---------------------------------------------------------------------------
__global__ void k_scan_partial(const int* __restrict__ cnt,
                               int* __restrict__ partial) {
    __shared__ int sdata[256];
    int tid = threadIdx.x;
    sdata[tid] = cnt[blockIdx.x * 256 + tid];
    __syncthreads();
    for (int s = 128; s > 0; s >>= 1) {
        if (tid < s) sdata[tid] += sdata[tid + s];
        __syncthreads();
    }
    if (tid == 0) partial[blockIdx.x] = sdata[0];
}

// ---------------------------------------------------------------------------
// Scan step 2: single-block exclusive scan of the 1960 partials.
// Round-15: FUSED with the sub-bucket scan (formerly k_subscan) -- saves a
// launch. Subscan runs with all 1024 threads, 2 cells each (2048 >= 1563).
// ---------------------------------------------------------------------------
__global__ void k_scan_top(int* __restrict__ partial,
                           int* __restrict__ subcnt,
                           int* __restrict__ subcur) {
    __shared__ int buf[1024];
    __shared__ int carry_s;
    int tid = threadIdx.x;
    if (tid == 0) carry_s = 0;
    __syncthreads();
    for (int base = 0; base < SBLKS; base += 1024) {
        int i = base + tid;
        int c = carry_s;
        int orig = (i < SBLKS) ? partial[i] : 0;
        buf[tid] = orig;
        __syncthreads();
        for (int off = 1; off < 1024; off <<= 1) {
            int t = (tid >= off) ? buf[tid - off] : 0;
            __syncthreads();
            buf[tid] += t;
            __syncthreads();
        }
        if (i < SBLKS) partial[i] = buf[tid] - orig + c;
        __syncthreads();
        if (tid == 0) carry_s = c + buf[1023];
        __syncthreads();
    }
    // ---- fused subscan: exclusive scan of 1563 sub-bucket counts ----
    int c0 = tid * 2, c1 = tid * 2 + 1;
    int v0 = (c0 < NSUB) ? subcnt[c0] : 0;
    int v1 = (c1 < NSUB) ? subcnt[c1] : 0;
    int sum = v0 + v1;
    buf[tid] = sum;
    __syncthreads();
    for (int off = 1; off < 1024; off <<= 1) {
        int t = (tid >= off) ? buf[tid - off] : 0;
        __syncthreads();
        buf[tid] += t;
        __syncthreads();
    }
    int run = buf[tid] - sum;
    if (c0 < NSUB) { subcnt[c0] = run; subcur[c0] = run; run += v0; }
    if (c1 < NSUB) { subcnt[c1] = run; subcur[c1] = run; }
    if (tid == 0) subcnt[NSUB] = NEDGES;
}

// ---------------------------------------------------------------------------
// Scan step 3: apply -- in-place exclusive scan of cnt
// ---------------------------------------------------------------------------
__global__ void k_scan_apply(int* __restrict__ cnt,
                             const int* __restrict__ partial) {
    __shared__ int buf[256];
    int tid = threadIdx.x;
    int i = blockIdx.x * 256 + tid;
    int v = cnt[i];
    buf[tid] = v;
    __syncthreads();
    for (int off = 1; off < 256; off <<= 1) {
        int t = (tid >= off) ? buf[tid - off] : 0;
        __syncthreads();
        buf[tid] += t;
        __syncthreads();
    }
    cnt[i] = buf[tid] - v + partial[blockIdx.x];
}

// ---------------------------------------------------------------------------
// P2: TILE-STAGED coarse scatter (round-12 de-barriered version).
// ---------------------------------------------------------------------------
__global__ void k_part_scatter(const float* __restrict__ r,
                               const int* __restrict__ src,
                               const int* __restrict__ dst,
                               const int* __restrict__ cnt,
                               float2* __restrict__ dstpart,
                               unsigned short* __restrict__ srcpart) {
    __shared__ int curD[NB], curS[NB];     // running global cursors
    __shared__ int hD[NB], hS[NB];         // tile hist, then tile cursor
    __shared__ int baseD[NB], baseS[NB];   // tile-local exclusive base
    __shared__ int segD[NB], segS[NB];     // global cursor snapshot at tile start
    __shared__ int wsum[4];                // cross-wave scan fixup
    __shared__ float stW[TILE];            //  5 KB staged weights
    __shared__ int   stK[TILE];            //  5 KB staged keys
    __shared__ int   ddD[TILE];            //  5 KB their global slots
    __shared__ unsigned short stS[TILE];   //2.5 KB staged src locals
    __shared__ int   ddS[TILE];            //  5 KB their global slots

    int tid = threadIdx.x, k = blockIdx.x;
    int lane = tid & 63, wv = tid >> 6;
    if (tid < NB) {
        curD[tid] = cnt[tid * PBLK + k];
        curS[tid] = cnt[(NB + tid) * PBLK + k] - NEDGES;
    }
    __syncthreads();

    int base = k * EPB;
    for (int t = 0; t < NTILE; t++) {
        int tbase = base + t * TILE;
        if (tid < NB) { hD[tid] = 0; hS[tid] = 0; }
        __syncthreads();
        // pass A: tile histograms
        for (int i = tid; i < TILE; i += 256) {
            int e = tbase + i;
            atomicAdd(&hD[dst[e] >> LBITS], 1);
            atomicAdd(&hS[src[e] >> LBITS], 1);
        }
        __syncthreads();
        // --- scan dst plane: 6-step shfl wave scan + 4-partial fixup ---
        {
            int v = (tid < NB) ? hD[tid] : 0;
            int x = v;
#pragma unroll
            for (int off = 1; off < 64; off <<= 1) {
                int tv = __shfl_up(x, off, 64);
                if (lane >= off) x += tv;
            }
            if (lane == 63) wsum[wv] = x;
            __syncthreads();
            if (tid == 0) {
                int a = 0;
#pragma unroll
                for (int wvi = 0; wvi < 4; wvi++) { int tv = wsum[wvi]; wsum[wvi] = a; a += tv; }
            }
            __syncthreads();
            int excl = x - v + wsum[wv];
            if (tid < NB) {
                baseD[tid] = excl;
                segD[tid] = curD[tid];
                curD[tid] += v;
                hD[tid] = excl;        // reuse as tile cursor
            }
        }
        __syncthreads();
        // --- scan src plane ---
        {
            int v = (tid < NB) ? hS[tid] : 0;
            int x = v;
#pragma unroll
            for (int off = 1; off < 64; off <<= 1) {
                int tv = __shfl_up(x, off, 64);
                if (lane >= off) x += tv;
            }
            if (lane == 63) wsum[wv] = x;
            __syncthreads();
            if (tid == 0) {
                int a = 0;
#pragma unroll
                for (int wvi = 0; wvi < 4; wvi++) { int tv = wsum[wvi]; wsum[wvi] = a; a += tv; }
            }
            __syncthreads();
            int excl = x - v + wsum[wv];
            if (tid < NB) {
                baseS[tid] = excl;
                segS[tid] = curS[tid];
                curS[tid] += v;
                hS[tid] = excl;
            }
        }
        __syncthreads();
        // pass B: stage records cell-ordered (src/dst re-read is L2/L3-hot)
        for (int i = tid; i < TILE; i += 256) {
            int e = tbase + i;
            int s = src[e], d = dst[e];
            float x = r[3 * e + 0];
            float y = r[3 * e + 1];
            float z = r[3 * e + 2];
            float w = expf(-(x * x + y * y + z * z));
            int cd = d >> LBITS;
            int idx = atomicAdd(&hD[cd], 1);
            stW[idx] = w;
            stK[idx] = (s << LBITS) | (d & LMASK);
            ddD[idx] = segD[cd] + (idx - baseD[cd]);
            int cs = s >> LBITS;
            int ids = atomicAdd(&hS[cs], 1);
            stS[ids] = (unsigned short)(s & LMASK);
            ddS[ids] = segS[cs] + (ids - baseS[cs]);
        }
        __syncthreads();
        // pass C: coalesced copy-out
        for (int i = tid; i < TILE; i += 256) {
            dstpart[ddD[i]] = make_float2(stW[i], __int_as_float(stK[i]));
            srcpart[ddS[i]] = stS[i];
        }
        __syncthreads();
    }
}

// ---------------------------------------------------------------------------
// P3s: per-bucket out-degree histogram (LDS) -> inv_sqrt_out.
// Runs BEFORE k_refine because srcpart aliases the csr/dstfine region.
// ---------------------------------------------------------------------------
__global__ void k_bucket_odeg(const unsigned short* __restrict__ srcpart,
                              const int* __restrict__ cnt,
                              float* __restrict__ inv_out) {
    __shared__ int hist[LSIZE];
    int tid = threadIdx.x, b = blockIdx.x;
    int bstart = cnt[(NB + b) * PBLK] - NEDGES;
    int bend = (b == NB - 1) ? NEDGES : (cnt[(NB + b + 1) * PBLK] - NEDGES);
    for (int l = tid; l < LSIZE; l += 256) hist[l] = 0;
    __syncthreads();
    for (int p = bstart + tid; p < bend; p += 256)
        atomicAdd(&hist[srcpart[p]], 1);
    __syncthreads();
    for (int l = tid; l < LSIZE; l += 256) {
        int n = (b << LBITS) + l;
        if (n < NNODES) {
            int c = hist[l];
            inv_out[n] = rsqrtf((float)(c < 1 ? 1 : c));
        }
    }
}

// ---------------------------------------------------------------------------
// 8-way refine, coarse bucket -> 128-node sub-buckets (round-4-proven).
// ---------------------------------------------------------------------------
__global__ void k_refine(const float2* __restrict__ dstpart,
                         const int* __restrict__ cnt,
                         int* __restrict__ subcur,
                         float2* __restrict__ dstfine) {
    int p = blockIdx.x >> 3;          // parent bucket
    int q = blockIdx.x & 7;           // eighth of its range
    int bstart = cnt[p * PBLK];
    int bend = (p == NB - 1) ? NEDGES : cnt[(p + 1) * PBLK];
    int sz = bend - bstart;
    int qs = bstart + (int)(((long long)sz * q) >> 3);
    int qe = bstart + (int)(((long long)sz * (q + 1)) >> 3);
    int lane = threadIdx.x & 63;
    int wv = threadIdx.x >> 6;        // 4 waves per block

    for (int base = qs + wv * 64; base < qe; base += 256) {
        int i = base + lane;
        bool act = (i < qe);
        float2 rec = make_float2(0.0f, 0.0f);
        if (act) rec = dstpart[i];
        unsigned pk = __float_as_uint(rec.y);
        int s3 = (pk >> SUBSH) & 7;   // sub index within parent
        unsigned long long b0 = __ballot(s3 & 1);
        unsigned long long b1 = __ballot(s3 & 2);
        unsigned long long b2 = __ballot(s3 & 4);
        unsigned long long am = __ballot(act);
        unsigned long long M = ((s3 & 1) ? b0 : ~b0)
                             & ((s3 & 2) ? b1 : ~b1)
                             & ((s3 & 4) ? b2 : ~b2) & am;
        if (act) {
            int cj = __popcll(M);
            int rank = __popcll(M & ((1ull << lane) - 1ull));
            int leader = __ffsll((unsigned long long)M) - 1;
            int gb = 0;
            if (lane == leader) gb = atomicAdd(&subcur[p * 8 + s3], cj);
            gb = __shfl(gb, leader, 64);
            dstfine[gb + rank] = rec;
        }
    }
}

// ---------------------------------------------------------------------------
// P3d: per-sub-bucket CSR build (round-3-proven), IN PLACE.
// ---------------------------------------------------------------------------
__global__ void k_bucket_csr(float2* __restrict__ data,
                             const int* __restrict__ subscan,
                             int* __restrict__ row_ptr,
                             float* __restrict__ inv_in) {
    __shared__ int hist[SKPAD];      //  7,168 B
    __shared__ int sbuf[256];        //  1,024 B
    __shared__ float2 stout[SMAX];   // 40,960 B
    int tid = threadIdx.x;
    int sub = blockIdx.x;
    int substart = subscan[sub];
    int subend = subscan[sub + 1];
    int sz = subend - substart;

    for (int j = tid; j < SKPAD; j += 256) hist[j] = 0;
    __syncthreads();
    // count keys over own range only
    for (int p = substart + tid; p < subend; p += 256) {
        unsigned pk = __float_as_uint(data[p].y);
        atomicAdd(&hist[(pk & 127u) * NCHK + (pk >> 24)], 1);
    }
    __syncthreads();
    // exclusive scan over the 1792 (padded) keys
    int kb = tid * SKPT;
    int sum = 0;
#pragma unroll
    for (int j = 0; j < SKPT; j++) sum += hist[kb + j];
    sbuf[tid] = sum;
    __syncthreads();
    for (int off = 1; off < 256; off <<= 1) {
        int tv = (tid >= off) ? sbuf[tid - off] : 0;
        __syncthreads();
        sbuf[tid] += tv;
        __syncthreads();
    }
    int run = sbuf[tid] - sum + substart;   // global cursor for own keys
#pragma unroll
    for (int j = 0; j < SKPT; j++) {
        int c = hist[kb + j];
        hist[kb + j] = run;
        run += c;
    }
    __syncthreads();
    // rows: start = cursor at key l*NCHK (read BEFORE placement mutates)
    if (tid < SUBN) {
        int l = tid;
        int rs = hist[l * NCHK];
        int re = (l == SUBN - 1) ? subend : hist[(l + 1) * NCHK];
        int n = (sub << SUBSH) + l;
        if (n < NNODES) {
            row_ptr[n] = rs;
            int c = re - rs;
            inv_in[n] = rsqrtf((float)(c < 1 ? 1 : c));
        }
    }
    __syncthreads();
    // placement into LDS staging (reads own range only; no global writes yet)
    if (sz <= SMAX) {
        for (int p = substart + tid; p < subend; p += 256) {
            float2 rec = data[p];
            unsigned pk = __float_as_uint(rec.y);
            int pos = atomicAdd(&hist[(pk & 127u) * NCHK + (pk >> 24)], 1);
            stout[pos - substart] = make_float2(rec.x, __int_as_float((int)(pk >> LBITS)));
        }
        __syncthreads();
        // coalesced copy-out (all reads of own range completed above)
        for (int i = tid; i < sz; i += 256)
            data[substart + i] = stout[i];
    } else {
        // overflow fallback (statistically unreachable: SMAX = mean + 16 sigma)
        for (int p = substart + tid; p < subend; p += 256) {
            float2 rec = data[p];
            unsigned pk = __float_as_uint(rec.y);
            int pos = atomicAdd(&hist[(pk & 127u) * NCHK + (pk >> 24)], 1);
            data[pos] = make_float2(rec.x, __int_as_float((int)(pk >> LBITS)));
        }
    }
}

// ---------------------------------------------------------------------------
// K5: hs[n,:] = (A[n,:] @ W_emb + b_emb) * inv_sqrt_out[n], padded rows
// ---------------------------------------------------------------------------
__global__ void k_embed(const float* __restrict__ A,
                        const float* __restrict__ Wemb,
                        const float* __restrict__ bemb,
                        const float* __restrict__ inv_out,
                        float* __restrict__ hs) {
    __shared__ float sW[FIN * WID];
    __shared__ float sb[WID];
    for (int i = threadIdx.x; i < FIN * WID; i += blockDim.x) sW[i] = Wemb[i];
    if (threadIdx.x < WID) sb[threadIdx.x] = bemb[threadIdx.x];
    __syncthreads();

    int n = blockIdx.x * blockDim.x + threadIdx.x;
    if (n >= NNODES) return;

    float acc[WID];
#pragma unroll
    for (int k = 0; k < WID; k++) acc[k] = sb[k];

    const float4* row4 = reinterpret_cast<const float4*>(A + (size_t)n * FIN);
#pragma unroll
    for (int f4 = 0; f4 < FIN / 4; f4++) {
        float4 v = row4[f4];
        int f = f4 * 4;
#pragma unroll
        for (int k = 0; k < WID; k++) acc[k] += v.x * sW[(f + 0) * WID + k];
#pragma unroll
        for (int k = 0; k < WID; k++) acc[k] += v.y * sW[(f + 1) * WID + k];
#pragma unroll
        for (int k = 0; k < WID; k++) acc[k] += v.z * sW[(f + 2) * WID + k];
#pragma unroll
        for (int k = 0; k < WID; k++) acc[k] += v.w * sW[(f + 3) * WID + k];
    }

    float sc = inv_out[n];
    float* out = hs + (size_t)n * HPAD;
    float4 o0 = make_float4(acc[0] * sc, acc[1] * sc, acc[2] * sc, acc[3] * sc);
    float4 o1 = make_float4(acc[4] * sc, acc[5] * sc, acc[6] * sc, acc[7] * sc);
    float2 o2 = make_float2(acc[8] * sc, acc[9] * sc);
    *reinterpret_cast<float4*>(out + 0) = o0;
    *reinterpret_cast<float4*>(out + 4) = o1;
    *reinterpret_cast<float2*>(out + 8) = o2;
}

// ---------------------------------------------------------------------------
// K7 round-15: 8 lanes/node, ONE counted loop, no barriers, no chunk logic.
// The 4 iterations per lane are independent -> csr load + hs gathers of
// successive iterations pipeline. csr is 64 B/8-lane-group coalesced.
// Butterfly reduce (masks 1,2,4), fused 10x10 update + gconv2 projection.
// ---------------------------------------------------------------------------
__global__ void k_agg1(const float2* __restrict__ csr,
                       const int* __restrict__ row_ptr,
                       const float* __restrict__ hs,
                       const float* __restrict__ W1,
                       const float* __restrict__ b1,
                       const float* __restrict__ W2,
                       const float* __restrict__ inv_in,
                       const float* __restrict__ inv_out,
                       float* __restrict__ sproj) {
    __shared__ float sW1[WID * WID];
    __shared__ float sb1[WID];
    __shared__ float sW2[WID];
    for (int i = threadIdx.x; i < WID * WID; i += blockDim.x) sW1[i] = W1[i];
    if (threadIdx.x < WID) {
        sb1[threadIdx.x] = b1[threadIdx.x];
        sW2[threadIdx.x] = W2[threadIdx.x];
    }
    __syncthreads();

    int tid = threadIdx.x;
    int sub = tid & (LPN - 1);
    int n = blockIdx.x * NPB + (tid >> LPNSH);   // all n < NNODES (6250*32 exact)

    int start = row_ptr[n];
    int end = (n == NNODES - 1) ? NEDGES : row_ptr[n + 1];

    float acc[WID];
#pragma unroll
    for (int k = 0; k < WID; k++) acc[k] = 0.0f;

    for (int p = start + sub; p < end; p += LPN) {
        float2 c2 = csr[p];
        float w = c2.x;
        int s = __float_as_int(c2.y);
        const float* hrow = hs + (size_t)s * HPAD;
        float4 a = *reinterpret_cast<const float4*>(hrow + 0);
        float4 b = *reinterpret_cast<const float4*>(hrow + 4);
        float2 cc = *reinterpret_cast<const float2*>(hrow + 8);
        acc[0] += w * a.x; acc[1] += w * a.y; acc[2] += w * a.z; acc[3] += w * a.w;
        acc[4] += w * b.x; acc[5] += w * b.y; acc[6] += w * b.z; acc[7] += w * b.w;
        acc[8] += w * cc.x; acc[9] += w * cc.y;
    }

    // butterfly reduce across the 8-lane group; every lane ends with the sum
#pragma unroll
    for (int m = 1; m < LPN; m <<= 1) {
#pragma unroll
        for (int k = 0; k < WID; k++) acc[k] += __shfl_xor(acc[k], m, 64);
    }

    if (sub != 0) return;
    float ii = inv_in[n];
    float dot = 0.0f;
#pragma unroll
    for (int j = 0; j < WID; j++) {
        float y = 0.0f;
#pragma unroll
        for (int k = 0; k < WID; k++) y += acc[k] * sW1[k * WID + j];
        y = y * ii + sb1[j];
        y = y > 0.0f ? y : 0.0f;
        dot += y * sW2[j];
    }
    sproj[n] = dot * inv_out[n];
}

// ---------------------------------------------------------------------------
// K8 round-15: gconv2 aggregate + graph pooling, FUSED with the final
// divide (formerly k_final) via a done-ticket: each block threadfences
// after its pooled atomics, takes a ticket; the LAST block re-reads pooled
// with agent-scope atomic loads and writes out[g] = pooled[g]/count(g).
// Saves one launch + its gap. __shfl clamps OOR lanes to SELF on AMD ->
// keep the lane+off<64 guard.
// ---------------------------------------------------------------------------
__global__ void k_agg2_pool(const float2* __restrict__ csr,
                            const int* __restrict__ row_ptr,
                            const float* __restrict__ sproj,
                            const float* __restrict__ inv_in,
                            const float* __restrict__ b2,
                            const int* __restrict__ graph_ids,
                            float* __restrict__ pooled,
                            int* __restrict__ done,
                            float* __restrict__ out) {
    __shared__ int ticket_s;
    int tid = threadIdx.x;
    int lane = tid & 63;
    int sub = tid & (LPN - 1);
    int n = blockIdx.x * NPB + (tid >> LPNSH);   // all n < NNODES

    int start = row_ptr[n];
    int end = (n == NNODES - 1) ? NEDGES : row_ptr[n + 1];
    float sum = 0.0f;
    for (int p = start + sub; p < end; p += LPN) {
        float2 c2 = csr[p];
        sum += c2.x * sproj[__float_as_int(c2.y)];
    }
#pragma unroll
    for (int m = 1; m < LPN; m <<= 1) sum += __shfl_xor(sum, m, 64);

    float v = sum * inv_in[n] + b2[0];
    int g = graph_ids[n];

    // segmented suffix-run reduce over the 8 node slots of the wave
#pragma unroll
    for (int off = LPN; off < 64; off <<= 1) {
        float vv = __shfl_down(v, off, 64);
        int gg = __shfl_down(g, off, 64);
        if (lane + off < 64 && gg == g) v += vv;
    }
    int gprev = __shfl_up(g, LPN, 64);
    bool head = (sub == 0) && (lane < LPN || gprev != g);
    if (head) atomicAdd(&pooled[g], v);

    // ---- fused finalization ----
    __threadfence();                 // make this thread's atomic visible
    __syncthreads();                 // all block threads fenced
    if (tid == 0) ticket_s = atomicAdd(done, 1);
    __syncthreads();
    if (ticket_s == AGG_BLKS - 1) {
        for (int g2 = tid; g2 < NGRAPHS; g2 += 256) {
            float pv = __hip_atomic_load(&pooled[g2], __ATOMIC_RELAXED,
                                         __HIP_MEMORY_SCOPE_AGENT);
            int lo = 0, hi = NNODES;
            while (lo < hi) { int m = (lo + hi) >> 1; if (graph_ids[m] < g2) lo = m + 1; else hi = m; }
            int first = lo;
            hi = NNODES;
            while (lo < hi) { int m = (lo + hi) >> 1; if (graph_ids[m] < g2 + 1) lo = m + 1; else hi = m; }
            int cnt = lo - first;
            out[g2] = pv / (float)(cnt > 0 ? cnt : 1);
        }
    }
}

// ---------------------------------------------------------------------------
extern "C" void kernel_launch(void* const* d_in, const int* in_sizes, int n_in,
                              void* d_out, int out_size, void* d_ws, size_t ws_size,
                              hipStream_t stream) {
    const float* atom = (const float*)d_in[0];
    const float* r    = (const float*)d_in[1];
    const float* Wemb = (const float*)d_in[2];
    const float* bemb = (const float*)d_in[3];
    const float* W1   = (const float*)d_in[4];
    const float* b1   = (const float*)d_in[5];
    const float* W2   = (const float*)d_in[6];
    const float* b2   = (const float*)d_in[7];
    const int*   src  = (const int*)d_in[8];
    const int*   dst  = (const int*)d_in[9];
    const int*   gids = (const int*)d_in[10];
    float* out = (float*)d_out;

    // Workspace layout (16B-aligned chunks), ~122 MB total.
    char* w = (char*)d_ws;
    float* pooled  = (float*)w;  w += (size_t)NGRAPHS * 4;          // zeroed
    int*   done    = (int*)w;    w += (size_t)16 * 4;               // zeroed (same memset)
    int*   subscan = (int*)w;    w += (size_t)NSUBP * 4;            // zeroed (6.4 KB)
    int*   subcur  = (int*)w;    w += (size_t)NSUBP * 4;
    int*   cnt     = (int*)w;    w += (size_t)CNT_N * 4;            // 2.0 MB
    int*   partial = (int*)w;    w += (size_t)((SBLKS + 3) & ~3) * 4;
    int*   row_ptr = (int*)w;    w += (size_t)((NNODES + 4) & ~3) * 4;
    float* inv_in  = (float*)w;  w += (size_t)NNODES * 4;
    float* inv_out = (float*)w;  w += (size_t)NNODES * 4;
    float* sproj   = (float*)w;  w += (size_t)NNODES * 4;
    float* hs      = (float*)w;  w += (size_t)NNODES * HPAD * 4;    // 12.8 MB
    float2* dstpart = (float2*)w; w += (size_t)NEDGES * 8;          // 51.2 MB
    float2* csrbuf  = (float2*)w; w += (size_t)NEDGES * 8;          // 51.2 MB
    // srcpart aliases csrbuf's first 12.8 MB: consumed by odeg BEFORE
    // k_refine writes dstfine into csrbuf; csr build then sorts IN PLACE.
    unsigned short* srcpart = (unsigned short*)csrbuf;

    hipMemsetAsync(pooled, 0, (size_t)NGRAPHS * 4 + 64, stream);   // pooled + done
    hipMemsetAsync(subscan, 0, (size_t)NSUBP * 4, stream);

    const int B = 256;

    k_part_count<<<PBLK, B, 0, stream>>>(src, dst, cnt, subscan);
    k_scan_partial<<<SBLKS, B, 0, stream>>>(cnt, partial);
    k_scan_top<<<1, 1024, 0, stream>>>(partial, subscan, subcur);
    k_scan_apply<<<SBLKS, B, 0, stream>>>(cnt, partial);
    k_part_scatter<<<PBLK, B, 0, stream>>>(r, src, dst, cnt, dstpart, srcpart);
    k_bucket_odeg<<<NB, B, 0, stream>>>(srcpart, cnt, inv_out);   // before refine (alias)
    k_refine<<<REF_GRID, B, 0, stream>>>(dstpart, cnt, subcur, csrbuf);
    k_bucket_csr<<<NSUB, B, 0, stream>>>(csrbuf, subscan, row_ptr, inv_in);
    k_embed<<<NBLK, B, 0, stream>>>(atom, Wemb, bemb, inv_out, hs);
    k_agg1<<<AGG_BLKS, B, 0, stream>>>(csrbuf, row_ptr, hs, W1, b1, W2, inv_in, inv_out, sproj);
    k_agg2_pool<<<AGG_BLKS, B, 0, stream>>>(csrbuf, row_ptr, sproj, inv_in, b2, gids,
                                            pooled, done, out);
}

// Round 9
// 837.939 us; speedup vs baseline: 1.3481x; 1.3481x over previous
//
#include <hip/hip_runtime.h>
#include <math.h>

#define NNODES  200000
#define NEDGES  6400000
#define NGRAPHS 512
#define FIN     92
#define WID     10
#define HPAD    16                     // hs row padded to 16 floats (64 B)
#define NBLK    ((NNODES + 255) / 256) // 782

// partition geometry -- round-16: SRC PLANE DELETED. Out-degree now comes
// from global atomicAdd in k_part_count (it already loads src[e]); the
// grid-starved k_bucket_odeg, the srcpart buffer, and scatter's second
// scan/staging plane are all gone. cnt holds dst cells only.
#define LBITS   10
#define LSIZE   1024                   // coarse dst bucket
#define LMASK   (LSIZE - 1)
#define NB      196                    // coarse buckets
#define SUBSH   7
#define SUBN    128                    // dst nodes per sub-bucket
#define NSUB    1563                   // ceil(200000/128) dst sub-buckets
#define NSUBP   1608                   // padded alloc (incl sentinel)
#define PBLK    1280                   // partition blocks (5/CU exact)
#define EPB     (NEDGES / PBLK)        // 5000 edges per partition block (exact)
#define TILE    1250                   // staging tile (EPB = 4 * TILE exactly)
#define NTILE   (EPB / TILE)           // 4
#define CNT_N   (NB * PBLK)            // 250,880 scan elements (dst only)
#define SBLKS   (CNT_N / 256)          // 980 scan blocks (exact)
#define REF_GRID (NB * 8)              // 1568 refine blocks (8 per parent)

// chunk-ordered rows (kept: csr sorted by (local, srcChunk))
#define CHBITS  14
#define NCHK    13                     // ceil(200000/16384) src chunks
#define SKEYS   (SUBN * NCHK)          // 1664 keys per sub-bucket
#define SKPAD   1792                   // 256*7 padded key array
#define SKPT    7                      // keys per thread in scan
#define SMAX    5120                   // LDS staging cap: mean 4096 + 16 sigma

// agg: 8 lanes/node, ONE counted loop, ZERO barriers (round-15 agg1 kept).
// Round-8 lesson (journal): __threadfence() on multi-XCD CDNA = per-block
// L2 writeback -> 6250 blocks paid ~500 us. The done-ticket fusion is
// REVERTED; k_final is a separate (cheap) launch again.
#define LPN     8
#define LPNSH   3
#define NPB     (256 / LPN)            // 32 nodes per block
#define AGG_BLKS (NNODES / NPB)        // 6250 (exact)

// ---------------------------------------------------------------------------
// P1: per-(bucket,block) dst counts via LDS histograms (sub-granularity,
// summed 8-way for the coarse cnt; totals into subcnt) + GLOBAL out-degree
// atomics (replaces the whole src plane + k_bucket_odeg).
// ---------------------------------------------------------------------------
__global__ void k_part_count(const int* __restrict__ src,
                             const int* __restrict__ dst,
                             int* __restrict__ cnt,
                             int* __restrict__ subcnt,
                             int* __restrict__ deg) {
    __shared__ int hSub[NSUB];
    int tid = threadIdx.x, k = blockIdx.x;
    for (int i = tid; i < NSUB; i += 256) hSub[i] = 0;
    __syncthreads();
    int base = k * EPB;
    for (int i = tid; i < EPB; i += 256) {
        int e = base + i;
        atomicAdd(&hSub[dst[e] >> SUBSH], 1);
        atomicAdd(&deg[src[e]], 1);            // global; scattered over 800 KB
    }
    __syncthreads();
    if (tid < NB) {
        int s = 0;
        int b0 = tid * 8;
#pragma unroll
        for (int j = 0; j < 8; j++) {
            int ix = b0 + j;
            if (ix < NSUB) s += hSub[ix];
        }
        cnt[tid * PBLK + k] = s;
    }
    for (int i = tid; i < NSUB; i += 256) {
        int v = hSub[i];
        if (v) atomicAdd(&subcnt[i], v);
    }
}

// ---------------------------------------------------------------------------
// Scan step 1: per-block (256-elem) partial sums of cnt
// ---------------------------------------------------------------------------
__global__ void k_scan_partial(const int* __restrict__ cnt,
                               int* __restrict__ partial) {
    __shared__ int sdata[256];
    int tid = threadIdx.x;
    sdata[tid] = cnt[blockIdx.x * 256 + tid];
    __syncthreads();
    for (int s = 128; s > 0; s >>= 1) {
        if (tid < s) sdata[tid] += sdata[tid + s];
        __syncthreads();
    }
    if (tid == 0) partial[blockIdx.x] = sdata[0];
}

// ---------------------------------------------------------------------------
// Scan step 2: single-block exclusive scan of the 980 partials, FUSED with
// the sub-bucket scan (2 cells/thread; 2048 >= 1563).
// ---------------------------------------------------------------------------
__global__ void k_scan_top(int* __restrict__ partial,
                           int* __restrict__ subcnt,
                           int* __restrict__ subcur) {
    __shared__ int buf[1024];
    __shared__ int carry_s;
    int tid = threadIdx.x;
    if (tid == 0) carry_s = 0;
    __syncthreads();
    for (int base = 0; base < SBLKS; base += 1024) {
        int i = base + tid;
        int c = carry_s;
        int orig = (i < SBLKS) ? partial[i] : 0;
        buf[tid] = orig;
        __syncthreads();
        for (int off = 1; off < 1024; off <<= 1) {
            int t = (tid >= off) ? buf[tid - off] : 0;
            __syncthreads();
            buf[tid] += t;
            __syncthreads();
        }
        if (i < SBLKS) partial[i] = buf[tid] - orig + c;
        __syncthreads();
        if (tid == 0) carry_s = c + buf[1023];
        __syncthreads();
    }
    // ---- fused subscan: exclusive scan of 1563 sub-bucket counts ----
    int c0 = tid * 2, c1 = tid * 2 + 1;
    int v0 = (c0 < NSUB) ? subcnt[c0] : 0;
    int v1 = (c1 < NSUB) ? subcnt[c1] : 0;
    int sum = v0 + v1;
    buf[tid] = sum;
    __syncthreads();
    for (int off = 1; off < 1024; off <<= 1) {
        int t = (tid >= off) ? buf[tid - off] : 0;
        __syncthreads();
        buf[tid] += t;
        __syncthreads();
    }
    int run = buf[tid] - sum;
    if (c0 < NSUB) { subcnt[c0] = run; subcur[c0] = run; run += v0; }
    if (c1 < NSUB) { subcnt[c1] = run; subcur[c1] = run; }
    if (tid == 0) subcnt[NSUB] = NEDGES;
}

// ---------------------------------------------------------------------------
// Scan step 3: apply -- in-place exclusive scan of cnt
// ---------------------------------------------------------------------------
__global__ void k_scan_apply(int* __restrict__ cnt,
                             const int* __restrict__ partial) {
    __shared__ int buf[256];
    int tid = threadIdx.x;
    int i = blockIdx.x * 256 + tid;
    int v = cnt[i];
    buf[tid] = v;
    __syncthreads();
    for (int off = 1; off < 256; off <<= 1) {
        int t = (tid >= off) ? buf[tid - off] : 0;
        __syncthreads();
        buf[tid] += t;
        __syncthreads();
    }
    cnt[i] = buf[tid] - v + partial[blockIdx.x];
}

// ---------------------------------------------------------------------------
// P2: TILE-STAGED coarse scatter, dst plane ONLY (src plane deleted).
// Per tile: hist -> one 2-barrier shfl wave-scan -> staged cell-ordered
// placement (SoA) -> coalesced copy-out. ~18 KB LDS.
// ---------------------------------------------------------------------------
__global__ void k_part_scatter(const float* __restrict__ r,
                               const int* __restrict__ src,
                               const int* __restrict__ dst,
                               const int* __restrict__ cnt,
                               float2* __restrict__ dstpart) {
    __shared__ int curD[NB], hD[NB], baseD[NB], segD[NB];
    __shared__ int wsum[4];                // cross-wave scan fixup
    __shared__ float stW[TILE];            //  5 KB staged weights
    __shared__ int   stK[TILE];            //  5 KB staged keys
    __shared__ int   ddD[TILE];            //  5 KB their global slots

    int tid = threadIdx.x, k = blockIdx.x;
    int lane = tid & 63, wv = tid >> 6;
    if (tid < NB) curD[tid] = cnt[tid * PBLK + k];
    __syncthreads();

    int base = k * EPB;
    for (int t = 0; t < NTILE; t++) {
        int tbase = base + t * TILE;
        if (tid < NB) hD[tid] = 0;
        __syncthreads();
        // pass A: tile histogram
        for (int i = tid; i < TILE; i += 256)
            atomicAdd(&hD[dst[tbase + i] >> LBITS], 1);
        __syncthreads();
        // scan: 6-step shfl wave scan + 4-partial fixup
        {
            int v = (tid < NB) ? hD[tid] : 0;
            int x = v;
#pragma unroll
            for (int off = 1; off < 64; off <<= 1) {
                int tv = __shfl_up(x, off, 64);
                if (lane >= off) x += tv;
            }
            if (lane == 63) wsum[wv] = x;
            __syncthreads();
            if (tid == 0) {
                int a = 0;
#pragma unroll
                for (int wvi = 0; wvi < 4; wvi++) { int tv = wsum[wvi]; wsum[wvi] = a; a += tv; }
            }
            __syncthreads();
            int excl = x - v + wsum[wv];
            if (tid < NB) {
                baseD[tid] = excl;
                segD[tid] = curD[tid];
                curD[tid] += v;
                hD[tid] = excl;        // reuse as tile cursor
            }
        }
        __syncthreads();
        // pass B: stage records cell-ordered (src/dst re-read is L2/L3-hot)
        for (int i = tid; i < TILE; i += 256) {
            int e = tbase + i;
            int s = src[e], d = dst[e];
            float x = r[3 * e + 0];
            float y = r[3 * e + 1];
            float z = r[3 * e + 2];
            float w = expf(-(x * x + y * y + z * z));
            int cd = d >> LBITS;
            int idx = atomicAdd(&hD[cd], 1);
            stW[idx] = w;
            stK[idx] = (s << LBITS) | (d & LMASK);
            ddD[idx] = segD[cd] + (idx - baseD[cd]);
        }
        __syncthreads();
        // pass C: coalesced copy-out
        for (int i = tid; i < TILE; i += 256)
            dstpart[ddD[i]] = make_float2(stW[i], __int_as_float(stK[i]));
        __syncthreads();
    }
}

// ---------------------------------------------------------------------------
// 8-way refine, coarse bucket -> 128-node sub-buckets (round-4-proven).
// Ballot multisplit, one global atomicAdd per (wave,sub) group, ascending
// write streams -> write amp ~1.
// ---------------------------------------------------------------------------
__global__ void k_refine(const float2* __restrict__ dstpart,
                         const int* __restrict__ cnt,
                         int* __restrict__ subcur,
                         float2* __restrict__ dstfine) {
    int p = blockIdx.x >> 3;          // parent bucket
    int q = blockIdx.x & 7;           // eighth of its range
    int bstart = cnt[p * PBLK];
    int bend = (p == NB - 1) ? NEDGES : cnt[(p + 1) * PBLK];
    int sz = bend - bstart;
    int qs = bstart + (int)(((long long)sz * q) >> 3);
    int qe = bstart + (int)(((long long)sz * (q + 1)) >> 3);
    int lane = threadIdx.x & 63;
    int wv = threadIdx.x >> 6;        // 4 waves per block

    for (int base = qs + wv * 64; base < qe; base += 256) {
        int i = base + lane;
        bool act = (i < qe);
        float2 rec = make_float2(0.0f, 0.0f);
        if (act) rec = dstpart[i];
        unsigned pk = __float_as_uint(rec.y);
        int s3 = (pk >> SUBSH) & 7;   // sub index within parent
        unsigned long long b0 = __ballot(s3 & 1);
        unsigned long long b1 = __ballot(s3 & 2);
        unsigned long long b2 = __ballot(s3 & 4);
        unsigned long long am = __ballot(act);
        unsigned long long M = ((s3 & 1) ? b0 : ~b0)
                             & ((s3 & 2) ? b1 : ~b1)
                             & ((s3 & 4) ? b2 : ~b2) & am;
        if (act) {
            int cj = __popcll(M);
            int rank = __popcll(M & ((1ull << lane) - 1ull));
            int leader = __ffsll((unsigned long long)M) - 1;
            int gb = 0;
            if (lane == leader) gb = atomicAdd(&subcur[p * 8 + s3], cj);
            gb = __shfl(gb, leader, 64);
            dstfine[gb + rank] = rec;
        }
    }
}

// ---------------------------------------------------------------------------
// P3d: per-sub-bucket CSR build (round-3-proven), IN PLACE.
// ---------------------------------------------------------------------------
__global__ void k_bucket_csr(float2* __restrict__ data,
                             const int* __restrict__ subscan,
                             int* __restrict__ row_ptr,
                             float* __restrict__ inv_in) {
    __shared__ int hist[SKPAD];      //  7,168 B
    __shared__ int sbuf[256];        //  1,024 B
    __shared__ float2 stout[SMAX];   // 40,960 B
    int tid = threadIdx.x;
    int sub = blockIdx.x;
    int substart = subscan[sub];
    int subend = subscan[sub + 1];
    int sz = subend - substart;

    for (int j = tid; j < SKPAD; j += 256) hist[j] = 0;
    __syncthreads();
    // count keys over own range only
    for (int p = substart + tid; p < subend; p += 256) {
        unsigned pk = __float_as_uint(data[p].y);
        atomicAdd(&hist[(pk & 127u) * NCHK + (pk >> 24)], 1);
    }
    __syncthreads();
    // exclusive scan over the 1792 (padded) keys
    int kb = tid * SKPT;
    int sum = 0;
#pragma unroll
    for (int j = 0; j < SKPT; j++) sum += hist[kb + j];
    sbuf[tid] = sum;
    __syncthreads();
    for (int off = 1; off < 256; off <<= 1) {
        int tv = (tid >= off) ? sbuf[tid - off] : 0;
        __syncthreads();
        sbuf[tid] += tv;
        __syncthreads();
    }
    int run = sbuf[tid] - sum + substart;   // global cursor for own keys
#pragma unroll
    for (int j = 0; j < SKPT; j++) {
        int c = hist[kb + j];
        hist[kb + j] = run;
        run += c;
    }
    __syncthreads();
    // rows: start = cursor at key l*NCHK (read BEFORE placement mutates)
    if (tid < SUBN) {
        int l = tid;
        int rs = hist[l * NCHK];
        int re = (l == SUBN - 1) ? subend : hist[(l + 1) * NCHK];
        int n = (sub << SUBSH) + l;
        if (n < NNODES) {
            row_ptr[n] = rs;
            int c = re - rs;
            inv_in[n] = rsqrtf((float)(c < 1 ? 1 : c));
        }
    }
    __syncthreads();
    // placement into LDS staging (reads own range only; no global writes yet)
    if (sz <= SMAX) {
        for (int p = substart + tid; p < subend; p += 256) {
            float2 rec = data[p];
            unsigned pk = __float_as_uint(rec.y);
            int pos = atomicAdd(&hist[(pk & 127u) * NCHK + (pk >> 24)], 1);
            stout[pos - substart] = make_float2(rec.x, __int_as_float((int)(pk >> LBITS)));
        }
        __syncthreads();
        // coalesced copy-out (all reads of own range completed above)
        for (int i = tid; i < sz; i += 256)
            data[substart + i] = stout[i];
    } else {
        // overflow fallback (statistically unreachable: SMAX = mean + 16 sigma)
        for (int p = substart + tid; p < subend; p += 256) {
            float2 rec = data[p];
            unsigned pk = __float_as_uint(rec.y);
            int pos = atomicAdd(&hist[(pk & 127u) * NCHK + (pk >> 24)], 1);
            data[pos] = make_float2(rec.x, __int_as_float((int)(pk >> LBITS)));
        }
    }
}

// ---------------------------------------------------------------------------
// K5: hs[n,:] = (A[n,:] @ W_emb + b_emb) * rsqrt(max(deg,1)), padded rows
// ---------------------------------------------------------------------------
__global__ void k_embed(const float* __restrict__ A,
                        const float* __restrict__ Wemb,
                        const float* __restrict__ bemb,
                        const int* __restrict__ deg,
                        float* __restrict__ hs) {
    __shared__ float sW[FIN * WID];
    __shared__ float sb[WID];
    for (int i = threadIdx.x; i < FIN * WID; i += blockDim.x) sW[i] = Wemb[i];
    if (threadIdx.x < WID) sb[threadIdx.x] = bemb[threadIdx.x];
    __syncthreads();

    int n = blockIdx.x * blockDim.x + threadIdx.x;
    if (n >= NNODES) return;

    float acc[WID];
#pragma unroll
    for (int k = 0; k < WID; k++) acc[k] = sb[k];

    const float4* row4 = reinterpret_cast<const float4*>(A + (size_t)n * FIN);
#pragma unroll
    for (int f4 = 0; f4 < FIN / 4; f4++) {
        float4 v = row4[f4];
        int f = f4 * 4;
#pragma unroll
        for (int k = 0; k < WID; k++) acc[k] += v.x * sW[(f + 0) * WID + k];
#pragma unroll
        for (int k = 0; k < WID; k++) acc[k] += v.y * sW[(f + 1) * WID + k];
#pragma unroll
        for (int k = 0; k < WID; k++) acc[k] += v.z * sW[(f + 2) * WID + k];
#pragma unroll
        for (int k = 0; k < WID; k++) acc[k] += v.w * sW[(f + 3) * WID + k];
    }

    int dg = deg[n];
    float sc = rsqrtf((float)(dg < 1 ? 1 : dg));
    float* out = hs + (size_t)n * HPAD;
    float4 o0 = make_float4(acc[0] * sc, acc[1] * sc, acc[2] * sc, acc[3] * sc);
    float4 o1 = make_float4(acc[4] * sc, acc[5] * sc, acc[6] * sc, acc[7] * sc);
    float2 o2 = make_float2(acc[8] * sc, acc[9] * sc);
    *reinterpret_cast<float4*>(out + 0) = o0;
    *reinterpret_cast<float4*>(out + 4) = o1;
    *reinterpret_cast<float2*>(out + 8) = o2;
}

// ---------------------------------------------------------------------------
// K7: 8 lanes/node, ONE counted loop, no barriers (round-15, kept).
// inv_out replaced by inline rsqrt(deg).
// ---------------------------------------------------------------------------
__global__ void k_agg1(const float2* __restrict__ csr,
                       const int* __restrict__ row_ptr,
                       const float* __restrict__ hs,
                       const float* __restrict__ W1,
                       const float* __restrict__ b1,
                       const float* __restrict__ W2,
                       const float* __restrict__ inv_in,
                       const int* __restrict__ deg,
                       float* __restrict__ sproj) {
    __shared__ float sW1[WID * WID];
    __shared__ float sb1[WID];
    __shared__ float sW2[WID];
    for (int i = threadIdx.x; i < WID * WID; i += blockDim.x) sW1[i] = W1[i];
    if (threadIdx.x < WID) {
        sb1[threadIdx.x] = b1[threadIdx.x];
        sW2[threadIdx.x] = W2[threadIdx.x];
    }
    __syncthreads();

    int tid = threadIdx.x;
    int sub = tid & (LPN - 1);
    int n = blockIdx.x * NPB + (tid >> LPNSH);   // all n < NNODES (6250*32 exact)

    int start = row_ptr[n];
    int end = (n == NNODES - 1) ? NEDGES : row_ptr[n + 1];

    float acc[WID];
#pragma unroll
    for (int k = 0; k < WID; k++) acc[k] = 0.0f;

    for (int p = start + sub; p < end; p += LPN) {
        float2 c2 = csr[p];
        float w = c2.x;
        int s = __float_as_int(c2.y);
        const float* hrow = hs + (size_t)s * HPAD;
        float4 a = *reinterpret_cast<const float4*>(hrow + 0);
        float4 b = *reinterpret_cast<const float4*>(hrow + 4);
        float2 cc = *reinterpret_cast<const float2*>(hrow + 8);
        acc[0] += w * a.x; acc[1] += w * a.y; acc[2] += w * a.z; acc[3] += w * a.w;
        acc[4] += w * b.x; acc[5] += w * b.y; acc[6] += w * b.z; acc[7] += w * b.w;
        acc[8] += w * cc.x; acc[9] += w * cc.y;
    }

    // butterfly reduce across the 8-lane group; every lane ends with the sum
#pragma unroll
    for (int m = 1; m < LPN; m <<= 1) {
#pragma unroll
        for (int k = 0; k < WID; k++) acc[k] += __shfl_xor(acc[k], m, 64);
    }

    if (sub != 0) return;
    float ii = inv_in[n];
    float dot = 0.0f;
#pragma unroll
    for (int j = 0; j < WID; j++) {
        float y = 0.0f;
#pragma unroll
        for (int k = 0; k < WID; k++) y += acc[k] * sW1[k * WID + j];
        y = y * ii + sb1[j];
        y = y > 0.0f ? y : 0.0f;
        dot += y * sW2[j];
    }
    int dg = deg[n];
    sproj[n] = dot * rsqrtf((float)(dg < 1 ? 1 : dg));
}

// ---------------------------------------------------------------------------
// K8: gconv2 aggregate + graph pooling (round-7 form, fence-free).
// __shfl clamps OOR lanes to SELF on AMD -> keep the lane+off<64 guard.
// ---------------------------------------------------------------------------
__global__ void k_agg2_pool(const float2* __restrict__ csr,
                            const int* __restrict__ row_ptr,
                            const float* __restrict__ sproj,
                            const float* __restrict__ inv_in,
                            const float* __restrict__ b2,
                            const int* __restrict__ graph_ids,
                            float* __restrict__ pooled) {
    int tid = threadIdx.x;
    int lane = tid & 63;
    int sub = tid & (LPN - 1);
    int n = blockIdx.x * NPB + (tid >> LPNSH);   // all n < NNODES

    int start = row_ptr[n];
    int end = (n == NNODES - 1) ? NEDGES : row_ptr[n + 1];
    float sum = 0.0f;
    for (int p = start + sub; p < end; p += LPN) {
        float2 c2 = csr[p];
        sum += c2.x * sproj[__float_as_int(c2.y)];
    }
#pragma unroll
    for (int m = 1; m < LPN; m <<= 1) sum += __shfl_xor(sum, m, 64);

    float v = sum * inv_in[n] + b2[0];
    int g = graph_ids[n];

    // segmented suffix-run reduce over the 8 node slots of the wave
#pragma unroll
    for (int off = LPN; off < 64; off <<= 1) {
        float vv = __shfl_down(v, off, 64);
        int gg = __shfl_down(g, off, 64);
        if (lane + off < 64 && gg == g) v += vv;
    }
    int gprev = __shfl_up(g, LPN, 64);
    bool head = (sub == 0) && (lane < LPN || gprev != g);
    if (head) atomicAdd(&pooled[g], v);
}

// ---------------------------------------------------------------------------
// K9: out[g] = pooled[g] / count(g); counts via binary search on sorted gids
// ---------------------------------------------------------------------------
__global__ void k_final(const float* __restrict__ pooled,
                        const int* __restrict__ gids,
                        float* __restrict__ out) {
    int g = blockIdx.x * blockDim.x + threadIdx.x;
    if (g >= NGRAPHS) return;
    int lo = 0, hi = NNODES;
    while (lo < hi) { int m = (lo + hi) >> 1; if (gids[m] < g) lo = m + 1; else hi = m; }
    int first = lo;
    hi = NNODES;
    while (lo < hi) { int m = (lo + hi) >> 1; if (gids[m] < g + 1) lo = m + 1; else hi = m; }
    int cnt = lo - first;
    out[g] = pooled[g] / (float)(cnt > 0 ? cnt : 1);
}

// ---------------------------------------------------------------------------
extern "C" void kernel_launch(void* const* d_in, const int* in_sizes, int n_in,
                              void* d_out, int out_size, void* d_ws, size_t ws_size,
                              hipStream_t stream) {
    const float* atom = (const float*)d_in[0];
    const float* r    = (const float*)d_in[1];
    const float* Wemb = (const float*)d_in[2];
    const float* bemb = (const float*)d_in[3];
    const float* W1   = (const float*)d_in[4];
    const float* b1   = (const float*)d_in[5];
    const float* W2   = (const float*)d_in[6];
    const float* b2   = (const float*)d_in[7];
    const int*   src  = (const int*)d_in[8];
    const int*   dst  = (const int*)d_in[9];
    const int*   gids = (const int*)d_in[10];
    float* out = (float*)d_out;

    // Workspace layout. First 4 regions are contiguous and zeroed by ONE
    // memset: pooled | deg | subscan | subcur.
    char* w = (char*)d_ws;
    float* pooled  = (float*)w;  w += (size_t)NGRAPHS * 4;          // 2 KB
    int*   deg     = (int*)w;    w += (size_t)NNODES * 4;           // 800 KB
    int*   subscan = (int*)w;    w += (size_t)NSUBP * 4;            // 6.4 KB
    int*   subcur  = (int*)w;    w += (size_t)NSUBP * 4;            // 6.4 KB
    size_t zbytes = (size_t)NGRAPHS * 4 + (size_t)NNODES * 4 + 2 * (size_t)NSUBP * 4;
    int*   cnt     = (int*)w;    w += (size_t)CNT_N * 4;            // 1.0 MB
    int*   partial = (int*)w;    w += (size_t)((SBLKS + 3) & ~3) * 4;
    int*   row_ptr = (int*)w;    w += (size_t)((NNODES + 4) & ~3) * 4;
    float* inv_in  = (float*)w;  w += (size_t)NNODES * 4;
    float* sproj   = (float*)w;  w += (size_t)NNODES * 4;
    float* hs      = (float*)w;  w += (size_t)NNODES * HPAD * 4;    // 12.8 MB
    float2* dstpart = (float2*)w; w += (size_t)NEDGES * 8;          // 51.2 MB
    float2* csrbuf  = (float2*)w; w += (size_t)NEDGES * 8;          // 51.2 MB

    hipMemsetAsync(pooled, 0, zbytes, stream);

    const int B = 256;

    k_part_count<<<PBLK, B, 0, stream>>>(src, dst, cnt, subscan, deg);
    k_scan_partial<<<SBLKS, B, 0, stream>>>(cnt, partial);
    k_scan_top<<<1, 1024, 0, stream>>>(partial, subscan, subcur);
    k_scan_apply<<<SBLKS, B, 0, stream>>>(cnt, partial);
    k_part_scatter<<<PBLK, B, 0, stream>>>(r, src, dst, cnt, dstpart);
    k_refine<<<REF_GRID, B, 0, stream>>>(dstpart, cnt, subcur, csrbuf);
    k_bucket_csr<<<NSUB, B, 0, stream>>>(csrbuf, subscan, row_ptr, inv_in);
    k_embed<<<NBLK, B, 0, stream>>>(atom, Wemb, bemb, deg, hs);
    k_agg1<<<AGG_BLKS, B, 0, stream>>>(csrbuf, row_ptr, hs, W1, b1, W2, inv_in, deg, sproj);
    k_agg2_pool<<<AGG_BLKS, B, 0, stream>>>(csrbuf, row_ptr, sproj, inv_in, b2, gids, pooled);
    k_final<<<(NGRAPHS + B - 1) / B, B, 0, stream>>>(pooled, gids, out);
}

// Round 10
// 686.325 us; speedup vs baseline: 1.6459x; 1.2209x over previous
//
#include <hip/hip_runtime.h>
#include <math.h>

#define NNODES  200000
#define NEDGES  6400000
#define NGRAPHS 512
#define FIN     92
#define WID     10
#define HPAD    16                     // hs row padded to 16 floats (64 B)
#define NBLK    ((NNODES + 255) / 256) // 782

// partition geometry (round-12 proven config). Round-9 lesson (journal):
// per-element device-scope atomics = HBM RMW ~32 B each (WRITE 215 MB,
// +230 us) -> src plane + LDS-histogram odeg RESTORED.
#define LBITS   10
#define LSIZE   1024                   // coarse bucket (both planes)
#define LMASK   (LSIZE - 1)
#define NB      196                    // coarse buckets
#define SUBSH   7
#define SUBN    128                    // dst nodes per sub-bucket
#define NSUB    1563                   // ceil(200000/128) dst sub-buckets
#define NSUBP   1608                   // padded alloc (incl sentinel)
#define PBLK    1280                   // partition blocks (5/CU exact)
#define EPB     (NEDGES / PBLK)        // 5000 edges per partition block (exact)
#define TILE    1250                   // staging tile (EPB = 4 * TILE exactly)
#define NTILE   (EPB / TILE)           // 4
#define CELLS   (2 * NB)               // 392 (dst plane + src plane)
#define CNT_N   (CELLS * PBLK)         // 501,760 scan elements
#define SBLKS   (CNT_N / 256)          // 1960 scan blocks (exact)
#define REF_GRID (NB * 8)              // 1568 refine blocks (8 per parent)

// chunk-ordered rows (kept: csr sorted by (local, srcChunk))
#define CHBITS  14
#define NCHK    13                     // ceil(200000/16384) src chunks
#define SKEYS   (SUBN * NCHK)          // 1664 keys per sub-bucket
#define SKPAD   1792                   // 256*7 padded key array
#define SKPT    7                      // keys per thread in scan
#define SMAX    5120                   // LDS staging cap: mean 4096 + 16 sigma

// agg: 8 lanes/node, ONE counted loop, ZERO barriers (round-15 agg1).
// Round-8 lesson: no __threadfence on per-block paths (L2 writeback).
#define LPN     8
#define LPNSH   3
#define NPB     (256 / LPN)            // 32 nodes per block
#define AGG_BLKS (NNODES / NPB)        // 6250 (exact)

// ---------------------------------------------------------------------------
// P1: per-(bucket,block) counts via LDS histograms; dst at sub-bucket
// granularity summed 8-way (coarse cnt) + totals into subcnt; src at
// coarse granularity into the cnt src plane. ZERO global hot-path atomics.
// ---------------------------------------------------------------------------
__global__ void k_part_count(const int* __restrict__ src,
                             const int* __restrict__ dst,
                             int* __restrict__ cnt,
                             int* __restrict__ subcnt) {
    __shared__ int hSub[NSUB];
    __shared__ int hS[NB];
    int tid = threadIdx.x, k = blockIdx.x;
    for (int i = tid; i < NSUB; i += 256) hSub[i] = 0;
    if (tid < NB) hS[tid] = 0;
    __syncthreads();
    int base = k * EPB;
    for (int i = tid; i < EPB; i += 256) {
        int e = base + i;
        atomicAdd(&hSub[dst[e] >> SUBSH], 1);
        atomicAdd(&hS[src[e] >> LBITS], 1);
    }
    __syncthreads();
    if (tid < NB) {
        int s = 0;
        int b0 = tid * 8;
#pragma unroll
        for (int j = 0; j < 8; j++) {
            int ix = b0 + j;
            if (ix < NSUB) s += hSub[ix];
        }
        cnt[tid * PBLK + k] = s;
        cnt[(NB + tid) * PBLK + k] = hS[tid];
    }
    for (int i = tid; i < NSUB; i += 256) {
        int v = hSub[i];
        if (v) atomicAdd(&subcnt[i], v);
    }
}

// ---------------------------------------------------------------------------
// Scan step 1: per-block (256-elem) partial sums of cnt
// ---------------------------------------------------------------------------
__global__ void k_scan_partial(const int* __restrict__ cnt,
                               int* __restrict__ partial) {
    __shared__ int sdata[256];
    int tid = threadIdx.x;
    sdata[tid] = cnt[blockIdx.x * 256 + tid];
    __syncthreads();
    for (int s = 128; s > 0; s >>= 1) {
        if (tid < s) sdata[tid] += sdata[tid + s];
        __syncthreads();
    }
    if (tid == 0) partial[blockIdx.x] = sdata[0];
}

// ---------------------------------------------------------------------------
// Scan step 2: single-block exclusive scan of the 1960 partials, FUSED with
// the sub-bucket scan (2 cells/thread; 2048 >= 1563).
// ---------------------------------------------------------------------------
__global__ void k_scan_top(int* __restrict__ partial,
                           int* __restrict__ subcnt,
                           int* __restrict__ subcur) {
    __shared__ int buf[1024];
    __shared__ int carry_s;
    int tid = threadIdx.x;
    if (tid == 0) carry_s = 0;
    __syncthreads();
    for (int base = 0; base < SBLKS; base += 1024) {
        int i = base + tid;
        int c = carry_s;
        int orig = (i < SBLKS) ? partial[i] : 0;
        buf[tid] = orig;
        __syncthreads();
        for (int off = 1; off < 1024; off <<= 1) {
            int t = (tid >= off) ? buf[tid - off] : 0;
            __syncthreads();
            buf[tid] += t;
            __syncthreads();
        }
        if (i < SBLKS) partial[i] = buf[tid] - orig + c;
        __syncthreads();
        if (tid == 0) carry_s = c + buf[1023];
        __syncthreads();
    }
    // ---- fused subscan: exclusive scan of 1563 sub-bucket counts ----
    int c0 = tid * 2, c1 = tid * 2 + 1;
    int v0 = (c0 < NSUB) ? subcnt[c0] : 0;
    int v1 = (c1 < NSUB) ? subcnt[c1] : 0;
    int sum = v0 + v1;
    buf[tid] = sum;
    __syncthreads();
    for (int off = 1; off < 1024; off <<= 1) {
        int t = (tid >= off) ? buf[tid - off] : 0;
        __syncthreads();
        buf[tid] += t;
        __syncthreads();
    }
    int run = buf[tid] - sum;
    if (c0 < NSUB) { subcnt[c0] = run; subcur[c0] = run; run += v0; }
    if (c1 < NSUB) { subcnt[c1] = run; subcur[c1] = run; }
    if (tid == 0) subcnt[NSUB] = NEDGES;
}

// ---------------------------------------------------------------------------
// Scan step 3: apply -- in-place exclusive scan of cnt
// ---------------------------------------------------------------------------
__global__ void k_scan_apply(int* __restrict__ cnt,
                             const int* __restrict__ partial) {
    __shared__ int buf[256];
    int tid = threadIdx.x;
    int i = blockIdx.x * 256 + tid;
    int v = cnt[i];
    buf[tid] = v;
    __syncthreads();
    for (int off = 1; off < 256; off <<= 1) {
        int t = (tid >= off) ? buf[tid - off] : 0;
        __syncthreads();
        buf[tid] += t;
        __syncthreads();
    }
    cnt[i] = buf[tid] - v + partial[blockIdx.x];
}

// ---------------------------------------------------------------------------
// P2: TILE-STAGED coarse scatter (round-12 de-barriered, dual plane).
// Per tile: hist -> two 2-barrier shfl wave-scans -> staged cell-ordered
// placement (SoA) -> coalesced copy-out. ZERO global atomics.
// ---------------------------------------------------------------------------
__global__ void k_part_scatter(const float* __restrict__ r,
                               const int* __restrict__ src,
                               const int* __restrict__ dst,
                               const int* __restrict__ cnt,
                               float2* __restrict__ dstpart,
                               unsigned short* __restrict__ srcpart) {
    __shared__ int curD[NB], curS[NB];     // running global cursors
    __shared__ int hD[NB], hS[NB];         // tile hist, then tile cursor
    __shared__ int baseD[NB], baseS[NB];   // tile-local exclusive base
    __shared__ int segD[NB], segS[NB];     // global cursor snapshot at tile start
    __shared__ int wsum[4];                // cross-wave scan fixup
    __shared__ float stW[TILE];            //  5 KB staged weights
    __shared__ int   stK[TILE];            //  5 KB staged keys
    __shared__ int   ddD[TILE];            //  5 KB their global slots
    __shared__ unsigned short stS[TILE];   //2.5 KB staged src locals
    __shared__ int   ddS[TILE];            //  5 KB their global slots

    int tid = threadIdx.x, k = blockIdx.x;
    int lane = tid & 63, wv = tid >> 6;
    if (tid < NB) {
        curD[tid] = cnt[tid * PBLK + k];
        curS[tid] = cnt[(NB + tid) * PBLK + k] - NEDGES;
    }
    __syncthreads();

    int base = k * EPB;
    for (int t = 0; t < NTILE; t++) {
        int tbase = base + t * TILE;
        if (tid < NB) { hD[tid] = 0; hS[tid] = 0; }
        __syncthreads();
        // pass A: tile histograms
        for (int i = tid; i < TILE; i += 256) {
            int e = tbase + i;
            atomicAdd(&hD[dst[e] >> LBITS], 1);
            atomicAdd(&hS[src[e] >> LBITS], 1);
        }
        __syncthreads();
        // --- scan dst plane: 6-step shfl wave scan + 4-partial fixup ---
        {
            int v = (tid < NB) ? hD[tid] : 0;
            int x = v;
#pragma unroll
            for (int off = 1; off < 64; off <<= 1) {
                int tv = __shfl_up(x, off, 64);
                if (lane >= off) x += tv;
            }
            if (lane == 63) wsum[wv] = x;
            __syncthreads();
            if (tid == 0) {
                int a = 0;
#pragma unroll
                for (int wvi = 0; wvi < 4; wvi++) { int tv = wsum[wvi]; wsum[wvi] = a; a += tv; }
            }
            __syncthreads();
            int excl = x - v + wsum[wv];
            if (tid < NB) {
                baseD[tid] = excl;
                segD[tid] = curD[tid];
                curD[tid] += v;
                hD[tid] = excl;        // reuse as tile cursor
            }
        }
        __syncthreads();
        // --- scan src plane ---
        {
            int v = (tid < NB) ? hS[tid] : 0;
            int x = v;
#pragma unroll
            for (int off = 1; off < 64; off <<= 1) {
                int tv = __shfl_up(x, off, 64);
                if (lane >= off) x += tv;
            }
            if (lane == 63) wsum[wv] = x;
            __syncthreads();
            if (tid == 0) {
                int a = 0;
#pragma unroll
                for (int wvi = 0; wvi < 4; wvi++) { int tv = wsum[wvi]; wsum[wvi] = a; a += tv; }
            }
            __syncthreads();
            int excl = x - v + wsum[wv];
            if (tid < NB) {
                baseS[tid] = excl;
                segS[tid] = curS[tid];
                curS[tid] += v;
                hS[tid] = excl;
            }
        }
        __syncthreads();
        // pass B: stage records cell-ordered (src/dst re-read is L2/L3-hot)
        for (int i = tid; i < TILE; i += 256) {
            int e = tbase + i;
            int s = src[e], d = dst[e];
            float x = r[3 * e + 0];
            float y = r[3 * e + 1];
            float z = r[3 * e + 2];
            float w = expf(-(x * x + y * y + z * z));
            int cd = d >> LBITS;
            int idx = atomicAdd(&hD[cd], 1);
            stW[idx] = w;
            stK[idx] = (s << LBITS) | (d & LMASK);
            ddD[idx] = segD[cd] + (idx - baseD[cd]);
            int cs = s >> LBITS;
            int ids = atomicAdd(&hS[cs], 1);
            stS[ids] = (unsigned short)(s & LMASK);
            ddS[ids] = segS[cs] + (ids - baseS[cs]);
        }
        __syncthreads();
        // pass C: coalesced copy-out
        for (int i = tid; i < TILE; i += 256) {
            dstpart[ddD[i]] = make_float2(stW[i], __int_as_float(stK[i]));
            srcpart[ddS[i]] = stS[i];
        }
        __syncthreads();
    }
}

// ---------------------------------------------------------------------------
// P3s: per-bucket out-degree histogram (LDS) -> inv_sqrt_out.
// Runs BEFORE k_refine because srcpart aliases the csr/dstfine region.
// ---------------------------------------------------------------------------
__global__ void k_bucket_odeg(const unsigned short* __restrict__ srcpart,
                              const int* __restrict__ cnt,
                              float* __restrict__ inv_out) {
    __shared__ int hist[LSIZE];
    int tid = threadIdx.x, b = blockIdx.x;
    int bstart = cnt[(NB + b) * PBLK] - NEDGES;
    int bend = (b == NB - 1) ? NEDGES : (cnt[(NB + b + 1) * PBLK] - NEDGES);
    for (int l = tid; l < LSIZE; l += 256) hist[l] = 0;
    __syncthreads();
    for (int p = bstart + tid; p < bend; p += 256)
        atomicAdd(&hist[srcpart[p]], 1);
    __syncthreads();
    for (int l = tid; l < LSIZE; l += 256) {
        int n = (b << LBITS) + l;
        if (n < NNODES) {
            int c = hist[l];
            inv_out[n] = rsqrtf((float)(c < 1 ? 1 : c));
        }
    }
}

// ---------------------------------------------------------------------------
// 8-way refine, coarse bucket -> 128-node sub-buckets (round-4-proven).
// Ballot multisplit, one global atomicAdd per (wave,sub) group, ascending
// write streams -> write amp ~1.
// ---------------------------------------------------------------------------
__global__ void k_refine(const float2* __restrict__ dstpart,
                         const int* __restrict__ cnt,
                         int* __restrict__ subcur,
                         float2* __restrict__ dstfine) {
    int p = blockIdx.x >> 3;          // parent bucket
    int q = blockIdx.x & 7;           // eighth of its range
    int bstart = cnt[p * PBLK];
    int bend = (p == NB - 1) ? NEDGES : cnt[(p + 1) * PBLK];
    int sz = bend - bstart;
    int qs = bstart + (int)(((long long)sz * q) >> 3);
    int qe = bstart + (int)(((long long)sz * (q + 1)) >> 3);
    int lane = threadIdx.x & 63;
    int wv = threadIdx.x >> 6;        // 4 waves per block

    for (int base = qs + wv * 64; base < qe; base += 256) {
        int i = base + lane;
        bool act = (i < qe);
        float2 rec = make_float2(0.0f, 0.0f);
        if (act) rec = dstpart[i];
        unsigned pk = __float_as_uint(rec.y);
        int s3 = (pk >> SUBSH) & 7;   // sub index within parent
        unsigned long long b0 = __ballot(s3 & 1);
        unsigned long long b1 = __ballot(s3 & 2);
        unsigned long long b2 = __ballot(s3 & 4);
        unsigned long long am = __ballot(act);
        unsigned long long M = ((s3 & 1) ? b0 : ~b0)
                             & ((s3 & 2) ? b1 : ~b1)
                             & ((s3 & 4) ? b2 : ~b2) & am;
        if (act) {
            int cj = __popcll(M);
            int rank = __popcll(M & ((1ull << lane) - 1ull));
            int leader = __ffsll((unsigned long long)M) - 1;
            int gb = 0;
            if (lane == leader) gb = atomicAdd(&subcur[p * 8 + s3], cj);
            gb = __shfl(gb, leader, 64);
            dstfine[gb + rank] = rec;
        }
    }
}

// ---------------------------------------------------------------------------
// P3d: per-sub-bucket CSR build (round-3-proven), IN PLACE.
// ---------------------------------------------------------------------------
__global__ void k_bucket_csr(float2* __restrict__ data,
                             const int* __restrict__ subscan,
                             int* __restrict__ row_ptr,
                             float* __restrict__ inv_in) {
    __shared__ int hist[SKPAD];      //  7,168 B
    __shared__ int sbuf[256];        //  1,024 B
    __shared__ float2 stout[SMAX];   // 40,960 B
    int tid = threadIdx.x;
    int sub = blockIdx.x;
    int substart = subscan[sub];
    int subend = subscan[sub + 1];
    int sz = subend - substart;

    for (int j = tid; j < SKPAD; j += 256) hist[j] = 0;
    __syncthreads();
    // count keys over own range only
    for (int p = substart + tid; p < subend; p += 256) {
        unsigned pk = __float_as_uint(data[p].y);
        atomicAdd(&hist[(pk & 127u) * NCHK + (pk >> 24)], 1);
    }
    __syncthreads();
    // exclusive scan over the 1792 (padded) keys
    int kb = tid * SKPT;
    int sum = 0;
#pragma unroll
    for (int j = 0; j < SKPT; j++) sum += hist[kb + j];
    sbuf[tid] = sum;
    __syncthreads();
    for (int off = 1; off < 256; off <<= 1) {
        int tv = (tid >= off) ? sbuf[tid - off] : 0;
        __syncthreads();
        sbuf[tid] += tv;
        __syncthreads();
    }
    int run = sbuf[tid] - sum + substart;   // global cursor for own keys
#pragma unroll
    for (int j = 0; j < SKPT; j++) {
        int c = hist[kb + j];
        hist[kb + j] = run;
        run += c;
    }
    __syncthreads();
    // rows: start = cursor at key l*NCHK (read BEFORE placement mutates)
    if (tid < SUBN) {
        int l = tid;
        int rs = hist[l * NCHK];
        int re = (l == SUBN - 1) ? subend : hist[(l + 1) * NCHK];
        int n = (sub << SUBSH) + l;
        if (n < NNODES) {
            row_ptr[n] = rs;
            int c = re - rs;
            inv_in[n] = rsqrtf((float)(c < 1 ? 1 : c));
        }
    }
    __syncthreads();
    // placement into LDS staging (reads own range only; no global writes yet)
    if (sz <= SMAX) {
        for (int p = substart + tid; p < subend; p += 256) {
            float2 rec = data[p];
            unsigned pk = __float_as_uint(rec.y);
            int pos = atomicAdd(&hist[(pk & 127u) * NCHK + (pk >> 24)], 1);
            stout[pos - substart] = make_float2(rec.x, __int_as_float((int)(pk >> LBITS)));
        }
        __syncthreads();
        // coalesced copy-out (all reads of own range completed above)
        for (int i = tid; i < sz; i += 256)
            data[substart + i] = stout[i];
    } else {
        // overflow fallback (statistically unreachable: SMAX = mean + 16 sigma)
        for (int p = substart + tid; p < subend; p += 256) {
            float2 rec = data[p];
            unsigned pk = __float_as_uint(rec.y);
            int pos = atomicAdd(&hist[(pk & 127u) * NCHK + (pk >> 24)], 1);
            data[pos] = make_float2(rec.x, __int_as_float((int)(pk >> LBITS)));
        }
    }
}

// ---------------------------------------------------------------------------
// K5: hs[n,:] = (A[n,:] @ W_emb + b_emb) * inv_sqrt_out[n], padded rows
// ---------------------------------------------------------------------------
__global__ void k_embed(const float* __restrict__ A,
                        const float* __restrict__ Wemb,
                        const float* __restrict__ bemb,
                        const float* __restrict__ inv_out,
                        float* __restrict__ hs) {
    __shared__ float sW[FIN * WID];
    __shared__ float sb[WID];
    for (int i = threadIdx.x; i < FIN * WID; i += blockDim.x) sW[i] = Wemb[i];
    if (threadIdx.x < WID) sb[threadIdx.x] = bemb[threadIdx.x];
    __syncthreads();

    int n = blockIdx.x * blockDim.x + threadIdx.x;
    if (n >= NNODES) return;

    float acc[WID];
#pragma unroll
    for (int k = 0; k < WID; k++) acc[k] = sb[k];

    const float4* row4 = reinterpret_cast<const float4*>(A + (size_t)n * FIN);
#pragma unroll
    for (int f4 = 0; f4 < FIN / 4; f4++) {
        float4 v = row4[f4];
        int f = f4 * 4;
#pragma unroll
        for (int k = 0; k < WID; k++) acc[k] += v.x * sW[(f + 0) * WID + k];
#pragma unroll
        for (int k = 0; k < WID; k++) acc[k] += v.y * sW[(f + 1) * WID + k];
#pragma unroll
        for (int k = 0; k < WID; k++) acc[k] += v.z * sW[(f + 2) * WID + k];
#pragma unroll
        for (int k = 0; k < WID; k++) acc[k] += v.w * sW[(f + 3) * WID + k];
    }

    float sc = inv_out[n];
    float* out = hs + (size_t)n * HPAD;
    float4 o0 = make_float4(acc[0] * sc, acc[1] * sc, acc[2] * sc, acc[3] * sc);
    float4 o1 = make_float4(acc[4] * sc, acc[5] * sc, acc[6] * sc, acc[7] * sc);
    float2 o2 = make_float2(acc[8] * sc, acc[9] * sc);
    *reinterpret_cast<float4*>(out + 0) = o0;
    *reinterpret_cast<float4*>(out + 4) = o1;
    *reinterpret_cast<float2*>(out + 8) = o2;
}

// ---------------------------------------------------------------------------
// K7: 8 lanes/node, ONE counted loop, no barriers (round-15, kept).
// 4 independent gather iterations per lane pipeline freely; csr reads are
// 64 B/8-lane-group coalesced. Butterfly reduce + fused 10x10 + proj.
// ---------------------------------------------------------------------------
__global__ void k_agg1(const float2* __restrict__ csr,
                       const int* __restrict__ row_ptr,
                       const float* __restrict__ hs,
                       const float* __restrict__ W1,
                       const float* __restrict__ b1,
                       const float* __restrict__ W2,
                       const float* __restrict__ inv_in,
                       const float* __restrict__ inv_out,
                       float* __restrict__ sproj) {
    __shared__ float sW1[WID * WID];
    __shared__ float sb1[WID];
    __shared__ float sW2[WID];
    for (int i = threadIdx.x; i < WID * WID; i += blockDim.x) sW1[i] = W1[i];
    if (threadIdx.x < WID) {
        sb1[threadIdx.x] = b1[threadIdx.x];
        sW2[threadIdx.x] = W2[threadIdx.x];
    }
    __syncthreads();

    int tid = threadIdx.x;
    int sub = tid & (LPN - 1);
    int n = blockIdx.x * NPB + (tid >> LPNSH);   // all n < NNODES (6250*32 exact)

    int start = row_ptr[n];
    int end = (n == NNODES - 1) ? NEDGES : row_ptr[n + 1];

    float acc[WID];
#pragma unroll
    for (int k = 0; k < WID; k++) acc[k] = 0.0f;

    for (int p = start + sub; p < end; p += LPN) {
        float2 c2 = csr[p];
        float w = c2.x;
        int s = __float_as_int(c2.y);
        const float* hrow = hs + (size_t)s * HPAD;
        float4 a = *reinterpret_cast<const float4*>(hrow + 0);
        float4 b = *reinterpret_cast<const float4*>(hrow + 4);
        float2 cc = *reinterpret_cast<const float2*>(hrow + 8);
        acc[0] += w * a.x; acc[1] += w * a.y; acc[2] += w * a.z; acc[3] += w * a.w;
        acc[4] += w * b.x; acc[5] += w * b.y; acc[6] += w * b.z; acc[7] += w * b.w;
        acc[8] += w * cc.x; acc[9] += w * cc.y;
    }

    // butterfly reduce across the 8-lane group; every lane ends with the sum
#pragma unroll
    for (int m = 1; m < LPN; m <<= 1) {
#pragma unroll
        for (int k = 0; k < WID; k++) acc[k] += __shfl_xor(acc[k], m, 64);
    }

    if (sub != 0) return;
    float ii = inv_in[n];
    float dot = 0.0f;
#pragma unroll
    for (int j = 0; j < WID; j++) {
        float y = 0.0f;
#pragma unroll
        for (int k = 0; k < WID; k++) y += acc[k] * sW1[k * WID + j];
        y = y * ii + sb1[j];
        y = y > 0.0f ? y : 0.0f;
        dot += y * sW2[j];
    }
    sproj[n] = dot * inv_out[n];
}

// ---------------------------------------------------------------------------
// K8: gconv2 aggregate + graph pooling (fence-free).
// __shfl clamps OOR lanes to SELF on AMD -> keep the lane+off<64 guard.
// ---------------------------------------------------------------------------
__global__ void k_agg2_pool(const float2* __restrict__ csr,
                            const int* __restrict__ row_ptr,
                            const float* __restrict__ sproj,
                            const float* __restrict__ inv_in,
                            const float* __restrict__ b2,
                            const int* __restrict__ graph_ids,
                            float* __restrict__ pooled) {
    int tid = threadIdx.x;
    int lane = tid & 63;
    int sub = tid & (LPN - 1);
    int n = blockIdx.x * NPB + (tid >> LPNSH);   // all n < NNODES

    int start = row_ptr[n];
    int end = (n == NNODES - 1) ? NEDGES : row_ptr[n + 1];
    float sum = 0.0f;
    for (int p = start + sub; p < end; p += LPN) {
        float2 c2 = csr[p];
        sum += c2.x * sproj[__float_as_int(c2.y)];
    }
#pragma unroll
    for (int m = 1; m < LPN; m <<= 1) sum += __shfl_xor(sum, m, 64);

    float v = sum * inv_in[n] + b2[0];
    int g = graph_ids[n];

    // segmented suffix-run reduce over the 8 node slots of the wave
#pragma unroll
    for (int off = LPN; off < 64; off <<= 1) {
        float vv = __shfl_down(v, off, 64);
        int gg = __shfl_down(g, off, 64);
        if (lane + off < 64 && gg == g) v += vv;
    }
    int gprev = __shfl_up(g, LPN, 64);
    bool head = (sub == 0) && (lane < LPN || gprev != g);
    if (head) atomicAdd(&pooled[g], v);
}

// ---------------------------------------------------------------------------
// K9: out[g] = pooled[g] / count(g); counts via binary search on sorted gids
// ---------------------------------------------------------------------------
__global__ void k_final(const float* __restrict__ pooled,
                        const int* __restrict__ gids,
                        float* __restrict__ out) {
    int g = blockIdx.x * blockDim.x + threadIdx.x;
    if (g >= NGRAPHS) return;
    int lo = 0, hi = NNODES;
    while (lo < hi) { int m = (lo + hi) >> 1; if (gids[m] < g) lo = m + 1; else hi = m; }
    int first = lo;
    hi = NNODES;
    while (lo < hi) { int m = (lo + hi) >> 1; if (gids[m] < g + 1) lo = m + 1; else hi = m; }
    int cnt = lo - first;
    out[g] = pooled[g] / (float)(cnt > 0 ? cnt : 1);
}

// ---------------------------------------------------------------------------
extern "C" void kernel_launch(void* const* d_in, const int* in_sizes, int n_in,
                              void* d_out, int out_size, void* d_ws, size_t ws_size,
                              hipStream_t stream) {
    const float* atom = (const float*)d_in[0];
    const float* r    = (const float*)d_in[1];
    const float* Wemb = (const float*)d_in[2];
    const float* bemb = (const float*)d_in[3];
    const float* W1   = (const float*)d_in[4];
    const float* b1   = (const float*)d_in[5];
    const float* W2   = (const float*)d_in[6];
    const float* b2   = (const float*)d_in[7];
    const int*   src  = (const int*)d_in[8];
    const int*   dst  = (const int*)d_in[9];
    const int*   gids = (const int*)d_in[10];
    float* out = (float*)d_out;

    // Workspace layout. First regions contiguous, zeroed by ONE memset:
    // pooled | subscan  (subcur filled by scan_top, no zero needed).
    char* w = (char*)d_ws;
    float* pooled  = (float*)w;  w += (size_t)NGRAPHS * 4;          // 2 KB
    int*   subscan = (int*)w;    w += (size_t)NSUBP * 4;            // 6.4 KB
    size_t zbytes = (size_t)NGRAPHS * 4 + (size_t)NSUBP * 4;
    int*   subcur  = (int*)w;    w += (size_t)NSUBP * 4;            // 6.4 KB
    int*   cnt     = (int*)w;    w += (size_t)CNT_N * 4;            // 2.0 MB
    int*   partial = (int*)w;    w += (size_t)((SBLKS + 3) & ~3) * 4;
    int*   row_ptr = (int*)w;    w += (size_t)((NNODES + 4) & ~3) * 4;
    float* inv_in  = (float*)w;  w += (size_t)NNODES * 4;
    float* inv_out = (float*)w;  w += (size_t)NNODES * 4;
    float* sproj   = (float*)w;  w += (size_t)NNODES * 4;
    float* hs      = (float*)w;  w += (size_t)NNODES * HPAD * 4;    // 12.8 MB
    float2* dstpart = (float2*)w; w += (size_t)NEDGES * 8;          // 51.2 MB
    float2* csrbuf  = (float2*)w; w += (size_t)NEDGES * 8;          // 51.2 MB
    // srcpart aliases csrbuf's first 12.8 MB: consumed by odeg BEFORE
    // k_refine writes dstfine into csrbuf; csr build then sorts IN PLACE.
    unsigned short* srcpart = (unsigned short*)csrbuf;

    hipMemsetAsync(pooled, 0, zbytes, stream);

    const int B = 256;

    k_part_count<<<PBLK, B, 0, stream>>>(src, dst, cnt, subscan);
    k_scan_partial<<<SBLKS, B, 0, stream>>>(cnt, partial);
    k_scan_top<<<1, 1024, 0, stream>>>(partial, subscan, subcur);
    k_scan_apply<<<SBLKS, B, 0, stream>>>(cnt, partial);
    k_part_scatter<<<PBLK, B, 0, stream>>>(r, src, dst, cnt, dstpart, srcpart);
    k_bucket_odeg<<<NB, B, 0, stream>>>(srcpart, cnt, inv_out);   // before refine (alias)
    k_refine<<<REF_GRID, B, 0, stream>>>(dstpart, cnt, subcur, csrbuf);
    k_bucket_csr<<<NSUB, B, 0, stream>>>(csrbuf, subscan, row_ptr, inv_in);
    k_embed<<<NBLK, B, 0, stream>>>(atom, Wemb, bemb, inv_out, hs);
    k_agg1<<<AGG_BLKS, B, 0, stream>>>(csrbuf, row_ptr, hs, W1, b1, W2, inv_in, inv_out, sproj);
    k_agg2_pool<<<AGG_BLKS, B, 0, stream>>>(csrbuf, row_ptr, sproj, inv_in, b2, gids, pooled);
    k_final<<<(NGRAPHS + B - 1) / B, B, 0, stream>>>(pooled, gids, out);
}

// Round 11
// 637.756 us; speedup vs baseline: 1.7712x; 1.0762x over previous
//
#include <hip/hip_runtime.h>
#include <hip/hip_fp16.h>
#include <math.h>

#define NNODES  200000
#define NEDGES  6400000
#define NGRAPHS 512
#define FIN     92
#define WID     10
#define HHALF   16                     // hs row = 10 fp16 padded to 16 (32 B)
#define NBLK    ((NNODES + 255) / 256) // 782

// partition geometry (round-12 proven config; round-10 composition base).
// Round-11 change (ONLY change vs round-10): hs stored as fp16 rows.
// Round-10 counters: agg1 FETCH 473 MB = 6.4M x 64 B lines + csr, 3.65 TB/s
// = random-line ceiling -> at the fp32 traffic floor. fp16 rows (32 B)
// halve payload AND shrink the working set to 6.4 MB (~ per-XCD L2) ->
// sibling-line reuse becomes possible.
#define LBITS   10
#define LSIZE   1024                   // coarse bucket (both planes)
#define LMASK   (LSIZE - 1)
#define NB      196                    // coarse buckets
#define SUBSH   7
#define SUBN    128                    // dst nodes per sub-bucket
#define NSUB    1563                   // ceil(200000/128) dst sub-buckets
#define NSUBP   1608                   // padded alloc (incl sentinel)
#define PBLK    1280                   // partition blocks (5/CU exact)
#define EPB     (NEDGES / PBLK)        // 5000 edges per partition block (exact)
#define TILE    1250                   // staging tile (EPB = 4 * TILE exactly)
#define NTILE   (EPB / TILE)           // 4
#define CELLS   (2 * NB)               // 392 (dst plane + src plane)
#define CNT_N   (CELLS * PBLK)         // 501,760 scan elements
#define SBLKS   (CNT_N / 256)          // 1960 scan blocks (exact)
#define REF_GRID (NB * 8)              // 1568 refine blocks (8 per parent)

// chunk-ordered rows (kept: csr sorted by (local, srcChunk))
#define CHBITS  14
#define NCHK    13                     // ceil(200000/16384) src chunks
#define SKEYS   (SUBN * NCHK)          // 1664 keys per sub-bucket
#define SKPAD   1792                   // 256*7 padded key array
#define SKPT    7                      // keys per thread in scan
#define SMAX    5120                   // LDS staging cap: mean 4096 + 16 sigma

// agg: 8 lanes/node, ONE counted loop, ZERO barriers.
// Journal: no __threadfence on per-block paths (r8); no per-element
// device atomics (r9); no global phase locks (r7).
#define LPN     8
#define LPNSH   3
#define NPB     (256 / LPN)            // 32 nodes per block
#define AGG_BLKS (NNODES / NPB)        // 6250 (exact)

// ---------------------------------------------------------------------------
// P1: per-(bucket,block) counts via LDS histograms; dst at sub-bucket
// granularity summed 8-way (coarse cnt) + totals into subcnt; src at
// coarse granularity into the cnt src plane. ZERO global hot-path atomics.
// ---------------------------------------------------------------------------
__global__ void k_part_count(const int* __restrict__ src,
                             const int* __restrict__ dst,
                             int* __restrict__ cnt,
                             int* __restrict__ subcnt) {
    __shared__ int hSub[NSUB];
    __shared__ int hS[NB];
    int tid = threadIdx.x, k = blockIdx.x;
    for (int i = tid; i < NSUB; i += 256) hSub[i] = 0;
    if (tid < NB) hS[tid] = 0;
    __syncthreads();
    int base = k * EPB;
    for (int i = tid; i < EPB; i += 256) {
        int e = base + i;
        atomicAdd(&hSub[dst[e] >> SUBSH], 1);
        atomicAdd(&hS[src[e] >> LBITS], 1);
    }
    __syncthreads();
    if (tid < NB) {
        int s = 0;
        int b0 = tid * 8;
#pragma unroll
        for (int j = 0; j < 8; j++) {
            int ix = b0 + j;
            if (ix < NSUB) s += hSub[ix];
        }
        cnt[tid * PBLK + k] = s;
        cnt[(NB + tid) * PBLK + k] = hS[tid];
    }
    for (int i = tid; i < NSUB; i += 256) {
        int v = hSub[i];
        if (v) atomicAdd(&subcnt[i], v);
    }
}

// ---------------------------------------------------------------------------
// Scan step 1: per-block (256-elem) partial sums of cnt
// ---------------------------------------------------------------------------
__global__ void k_scan_partial(const int* __restrict__ cnt,
                               int* __restrict__ partial) {
    __shared__ int sdata[256];
    int tid = threadIdx.x;
    sdata[tid] = cnt[blockIdx.x * 256 + tid];
    __syncthreads();
    for (int s = 128; s > 0; s >>= 1) {
        if (tid < s) sdata[tid] += sdata[tid + s];
        __syncthreads();
    }
    if (tid == 0) partial[blockIdx.x] = sdata[0];
}

// ---------------------------------------------------------------------------
// Scan step 2: single-block exclusive scan of the 1960 partials, FUSED with
// the sub-bucket scan (2 cells/thread; 2048 >= 1563).
// ---------------------------------------------------------------------------
__global__ void k_scan_top(int* __restrict__ partial,
                           int* __restrict__ subcnt,
                           int* __restrict__ subcur) {
    __shared__ int buf[1024];
    __shared__ int carry_s;
    int tid = threadIdx.x;
    if (tid == 0) carry_s = 0;
    __syncthreads();
    for (int base = 0; base < SBLKS; base += 1024) {
        int i = base + tid;
        int c = carry_s;
        int orig = (i < SBLKS) ? partial[i] : 0;
        buf[tid] = orig;
        __syncthreads();
        for (int off = 1; off < 1024; off <<= 1) {
            int t = (tid >= off) ? buf[tid - off] : 0;
            __syncthreads();
            buf[tid] += t;
            __syncthreads();
        }
        if (i < SBLKS) partial[i] = buf[tid] - orig + c;
        __syncthreads();
        if (tid == 0) carry_s = c + buf[1023];
        __syncthreads();
    }
    // ---- fused subscan: exclusive scan of 1563 sub-bucket counts ----
    int c0 = tid * 2, c1 = tid * 2 + 1;
    int v0 = (c0 < NSUB) ? subcnt[c0] : 0;
    int v1 = (c1 < NSUB) ? subcnt[c1] : 0;
    int sum = v0 + v1;
    buf[tid] = sum;
    __syncthreads();
    for (int off = 1; off < 1024; off <<= 1) {
        int t = (tid >= off) ? buf[tid - off] : 0;
        __syncthreads();
        buf[tid] += t;
        __syncthreads();
    }
    int run = buf[tid] - sum;
    if (c0 < NSUB) { subcnt[c0] = run; subcur[c0] = run; run += v0; }
    if (c1 < NSUB) { subcnt[c1] = run; subcur[c1] = run; }
    if (tid == 0) subcnt[NSUB] = NEDGES;
}

// ---------------------------------------------------------------------------
// Scan step 3: apply -- in-place exclusive scan of cnt
// ---------------------------------------------------------------------------
__global__ void k_scan_apply(int* __restrict__ cnt,
                             const int* __restrict__ partial) {
    __shared__ int buf[256];
    int tid = threadIdx.x;
    int i = blockIdx.x * 256 + tid;
    int v = cnt[i];
    buf[tid] = v;
    __syncthreads();
    for (int off = 1; off < 256; off <<= 1) {
        int t = (tid >= off) ? buf[tid - off] : 0;
        __syncthreads();
        buf[tid] += t;
        __syncthreads();
    }
    cnt[i] = buf[tid] - v + partial[blockIdx.x];
}

// ---------------------------------------------------------------------------
// P2: TILE-STAGED coarse scatter (round-12 de-barriered, dual plane).
// ---------------------------------------------------------------------------
__global__ void k_part_scatter(const float* __restrict__ r,
                               const int* __restrict__ src,
                               const int* __restrict__ dst,
                               const int* __restrict__ cnt,
                               float2* __restrict__ dstpart,
                               unsigned short* __restrict__ srcpart) {
    __shared__ int curD[NB], curS[NB];     // running global cursors
    __shared__ int hD[NB], hS[NB];         // tile hist, then tile cursor
    __shared__ int baseD[NB], baseS[NB];   // tile-local exclusive base
    __shared__ int segD[NB], segS[NB];     // global cursor snapshot at tile start
    __shared__ int wsum[4];                // cross-wave scan fixup
    __shared__ float stW[TILE];            //  5 KB staged weights
    __shared__ int   stK[TILE];            //  5 KB staged keys
    __shared__ int   ddD[TILE];            //  5 KB their global slots
    __shared__ unsigned short stS[TILE];   //2.5 KB staged src locals
    __shared__ int   ddS[TILE];            //  5 KB their global slots

    int tid = threadIdx.x, k = blockIdx.x;
    int lane = tid & 63, wv = tid >> 6;
    if (tid < NB) {
        curD[tid] = cnt[tid * PBLK + k];
        curS[tid] = cnt[(NB + tid) * PBLK + k] - NEDGES;
    }
    __syncthreads();

    int base = k * EPB;
    for (int t = 0; t < NTILE; t++) {
        int tbase = base + t * TILE;
        if (tid < NB) { hD[tid] = 0; hS[tid] = 0; }
        __syncthreads();
        // pass A: tile histograms
        for (int i = tid; i < TILE; i += 256) {
            int e = tbase + i;
            atomicAdd(&hD[dst[e] >> LBITS], 1);
            atomicAdd(&hS[src[e] >> LBITS], 1);
        }
        __syncthreads();
        // --- scan dst plane: 6-step shfl wave scan + 4-partial fixup ---
        {
            int v = (tid < NB) ? hD[tid] : 0;
            int x = v;
#pragma unroll
            for (int off = 1; off < 64; off <<= 1) {
                int tv = __shfl_up(x, off, 64);
                if (lane >= off) x += tv;
            }
            if (lane == 63) wsum[wv] = x;
            __syncthreads();
            if (tid == 0) {
                int a = 0;
#pragma unroll
                for (int wvi = 0; wvi < 4; wvi++) { int tv = wsum[wvi]; wsum[wvi] = a; a += tv; }
            }
            __syncthreads();
            int excl = x - v + wsum[wv];
            if (tid < NB) {
                baseD[tid] = excl;
                segD[tid] = curD[tid];
                curD[tid] += v;
                hD[tid] = excl;        // reuse as tile cursor
            }
        }
        __syncthreads();
        // --- scan src plane ---
        {
            int v = (tid < NB) ? hS[tid] : 0;
            int x = v;
#pragma unroll
            for (int off = 1; off < 64; off <<= 1) {
                int tv = __shfl_up(x, off, 64);
                if (lane >= off) x += tv;
            }
            if (lane == 63) wsum[wv] = x;
            __syncthreads();
            if (tid == 0) {
                int a = 0;
#pragma unroll
                for (int wvi = 0; wvi < 4; wvi++) { int tv = wsum[wvi]; wsum[wvi] = a; a += tv; }
            }
            __syncthreads();
            int excl = x - v + wsum[wv];
            if (tid < NB) {
                baseS[tid] = excl;
                segS[tid] = curS[tid];
                curS[tid] += v;
                hS[tid] = excl;
            }
        }
        __syncthreads();
        // pass B: stage records cell-ordered (src/dst re-read is L2/L3-hot)
        for (int i = tid; i < TILE; i += 256) {
            int e = tbase + i;
            int s = src[e], d = dst[e];
            float x = r[3 * e + 0];
            float y = r[3 * e + 1];
            float z = r[3 * e + 2];
            float w = expf(-(x * x + y * y + z * z));
            int cd = d >> LBITS;
            int idx = atomicAdd(&hD[cd], 1);
            stW[idx] = w;
            stK[idx] = (s << LBITS) | (d & LMASK);
            ddD[idx] = segD[cd] + (idx - baseD[cd]);
            int cs = s >> LBITS;
            int ids = atomicAdd(&hS[cs], 1);
            stS[ids] = (unsigned short)(s & LMASK);
            ddS[ids] = segS[cs] + (ids - baseS[cs]);
        }
        __syncthreads();
        // pass C: coalesced copy-out
        for (int i = tid; i < TILE; i += 256) {
            dstpart[ddD[i]] = make_float2(stW[i], __int_as_float(stK[i]));
            srcpart[ddS[i]] = stS[i];
        }
        __syncthreads();
    }
}

// ---------------------------------------------------------------------------
// P3s: per-bucket out-degree histogram (LDS) -> inv_sqrt_out.
// Runs BEFORE k_refine because srcpart aliases the csr/dstfine region.
// ---------------------------------------------------------------------------
__global__ void k_bucket_odeg(const unsigned short* __restrict__ srcpart,
                              const int* __restrict__ cnt,
                              float* __restrict__ inv_out) {
    __shared__ int hist[LSIZE];
    int tid = threadIdx.x, b = blockIdx.x;
    int bstart = cnt[(NB + b) * PBLK] - NEDGES;
    int bend = (b == NB - 1) ? NEDGES : (cnt[(NB + b + 1) * PBLK] - NEDGES);
    for (int l = tid; l < LSIZE; l += 256) hist[l] = 0;
    __syncthreads();
    for (int p = bstart + tid; p < bend; p += 256)
        atomicAdd(&hist[srcpart[p]], 1);
    __syncthreads();
    for (int l = tid; l < LSIZE; l += 256) {
        int n = (b << LBITS) + l;
        if (n < NNODES) {
            int c = hist[l];
            inv_out[n] = rsqrtf((float)(c < 1 ? 1 : c));
        }
    }
}

// ---------------------------------------------------------------------------
// 8-way refine, coarse bucket -> 128-node sub-buckets (round-4-proven).
// ---------------------------------------------------------------------------
__global__ void k_refine(const float2* __restrict__ dstpart,
                         const int* __restrict__ cnt,
                         int* __restrict__ subcur,
                         float2* __restrict__ dstfine) {
    int p = blockIdx.x >> 3;          // parent bucket
    int q = blockIdx.x & 7;           // eighth of its range
    int bstart = cnt[p * PBLK];
    int bend = (p == NB - 1) ? NEDGES : cnt[(p + 1) * PBLK];
    int sz = bend - bstart;
    int qs = bstart + (int)(((long long)sz * q) >> 3);
    int qe = bstart + (int)(((long long)sz * (q + 1)) >> 3);
    int lane = threadIdx.x & 63;
    int wv = threadIdx.x >> 6;        // 4 waves per block

    for (int base = qs + wv * 64; base < qe; base += 256) {
        int i = base + lane;
        bool act = (i < qe);
        float2 rec = make_float2(0.0f, 0.0f);
        if (act) rec = dstpart[i];
        unsigned pk = __float_as_uint(rec.y);
        int s3 = (pk >> SUBSH) & 7;   // sub index within parent
        unsigned long long b0 = __ballot(s3 & 1);
        unsigned long long b1 = __ballot(s3 & 2);
        unsigned long long b2 = __ballot(s3 & 4);
        unsigned long long am = __ballot(act);
        unsigned long long M = ((s3 & 1) ? b0 : ~b0)
                             & ((s3 & 2) ? b1 : ~b1)
                             & ((s3 & 4) ? b2 : ~b2) & am;
        if (act) {
            int cj = __popcll(M);
            int rank = __popcll(M & ((1ull << lane) - 1ull));
            int leader = __ffsll((unsigned long long)M) - 1;
            int gb = 0;
            if (lane == leader) gb = atomicAdd(&subcur[p * 8 + s3], cj);
            gb = __shfl(gb, leader, 64);
            dstfine[gb + rank] = rec;
        }
    }
}

// ---------------------------------------------------------------------------
// P3d: per-sub-bucket CSR build (round-3-proven), IN PLACE.
// ---------------------------------------------------------------------------
__global__ void k_bucket_csr(float2* __restrict__ data,
                             const int* __restrict__ subscan,
                             int* __restrict__ row_ptr,
                             float* __restrict__ inv_in) {
    __shared__ int hist[SKPAD];      //  7,168 B
    __shared__ int sbuf[256];        //  1,024 B
    __shared__ float2 stout[SMAX];   // 40,960 B
    int tid = threadIdx.x;
    int sub = blockIdx.x;
    int substart = subscan[sub];
    int subend = subscan[sub + 1];
    int sz = subend - substart;

    for (int j = tid; j < SKPAD; j += 256) hist[j] = 0;
    __syncthreads();
    // count keys over own range only
    for (int p = substart + tid; p < subend; p += 256) {
        unsigned pk = __float_as_uint(data[p].y);
        atomicAdd(&hist[(pk & 127u) * NCHK + (pk >> 24)], 1);
    }
    __syncthreads();
    // exclusive scan over the 1792 (padded) keys
    int kb = tid * SKPT;
    int sum = 0;
#pragma unroll
    for (int j = 0; j < SKPT; j++) sum += hist[kb + j];
    sbuf[tid] = sum;
    __syncthreads();
    for (int off = 1; off < 256; off <<= 1) {
        int tv = (tid >= off) ? sbuf[tid - off] : 0;
        __syncthreads();
        sbuf[tid] += tv;
        __syncthreads();
    }
    int run = sbuf[tid] - sum + substart;   // global cursor for own keys
#pragma unroll
    for (int j = 0; j < SKPT; j++) {
        int c = hist[kb + j];
        hist[kb + j] = run;
        run += c;
    }
    __syncthreads();
    // rows: start = cursor at key l*NCHK (read BEFORE placement mutates)
    if (tid < SUBN) {
        int l = tid;
        int rs = hist[l * NCHK];
        int re = (l == SUBN - 1) ? subend : hist[(l + 1) * NCHK];
        int n = (sub << SUBSH) + l;
        if (n < NNODES) {
            row_ptr[n] = rs;
            int c = re - rs;
            inv_in[n] = rsqrtf((float)(c < 1 ? 1 : c));
        }
    }
    __syncthreads();
    // placement into LDS staging (reads own range only; no global writes yet)
    if (sz <= SMAX) {
        for (int p = substart + tid; p < subend; p += 256) {
            float2 rec = data[p];
            unsigned pk = __float_as_uint(rec.y);
            int pos = atomicAdd(&hist[(pk & 127u) * NCHK + (pk >> 24)], 1);
            stout[pos - substart] = make_float2(rec.x, __int_as_float((int)(pk >> LBITS)));
        }
        __syncthreads();
        // coalesced copy-out (all reads of own range completed above)
        for (int i = tid; i < sz; i += 256)
            data[substart + i] = stout[i];
    } else {
        // overflow fallback (statistically unreachable: SMAX = mean + 16 sigma)
        for (int p = substart + tid; p < subend; p += 256) {
            float2 rec = data[p];
            unsigned pk = __float_as_uint(rec.y);
            int pos = atomicAdd(&hist[(pk & 127u) * NCHK + (pk >> 24)], 1);
            data[pos] = make_float2(rec.x, __int_as_float((int)(pk >> LBITS)));
        }
    }
}

// ---------------------------------------------------------------------------
// K5: hs[n,:] = fp16( (A[n,:] @ W_emb + b_emb) * inv_sqrt_out[n] ).
// Round-11: rows are 10 fp16 padded to 16 (32 B stride); written as
// uint4 + uint (20 B payload).
// ---------------------------------------------------------------------------
__global__ void k_embed(const float* __restrict__ A,
                        const float* __restrict__ Wemb,
                        const float* __restrict__ bemb,
                        const float* __restrict__ inv_out,
                        __half* __restrict__ hs) {
    __shared__ float sW[FIN * WID];
    __shared__ float sb[WID];
    for (int i = threadIdx.x; i < FIN * WID; i += blockDim.x) sW[i] = Wemb[i];
    if (threadIdx.x < WID) sb[threadIdx.x] = bemb[threadIdx.x];
    __syncthreads();

    int n = blockIdx.x * blockDim.x + threadIdx.x;
    if (n >= NNODES) return;

    float acc[WID];
#pragma unroll
    for (int k = 0; k < WID; k++) acc[k] = sb[k];

    const float4* row4 = reinterpret_cast<const float4*>(A + (size_t)n * FIN);
#pragma unroll
    for (int f4 = 0; f4 < FIN / 4; f4++) {
        float4 v = row4[f4];
        int f = f4 * 4;
#pragma unroll
        for (int k = 0; k < WID; k++) acc[k] += v.x * sW[(f + 0) * WID + k];
#pragma unroll
        for (int k = 0; k < WID; k++) acc[k] += v.y * sW[(f + 1) * WID + k];
#pragma unroll
        for (int k = 0; k < WID; k++) acc[k] += v.z * sW[(f + 2) * WID + k];
#pragma unroll
        for (int k = 0; k < WID; k++) acc[k] += v.w * sW[(f + 3) * WID + k];
    }

    float sc = inv_out[n];
    __half2 hp[5];
#pragma unroll
    for (int k2 = 0; k2 < 5; k2++)
        hp[k2] = __float22half2_rn(make_float2(acc[2 * k2] * sc, acc[2 * k2 + 1] * sc));
    unsigned int* hpu = reinterpret_cast<unsigned int*>(hp);
    __half* outp = hs + (size_t)n * HHALF;
    *reinterpret_cast<uint4*>(outp) = make_uint4(hpu[0], hpu[1], hpu[2], hpu[3]);
    *reinterpret_cast<unsigned int*>(outp + 8) = hpu[4];
}

// ---------------------------------------------------------------------------
// K7: 8 lanes/node, ONE counted loop, no barriers. Round-11: hs rows are
// fp16 (32 B): 2 loads/edge (uint4 + uint), 5x half2->float2 convert.
// Butterfly reduce + fused 10x10 + gconv2 projection.
// ---------------------------------------------------------------------------
__global__ void k_agg1(const float2* __restrict__ csr,
                       const int* __restrict__ row_ptr,
                       const __half* __restrict__ hs,
                       const float* __restrict__ W1,
                       const float* __restrict__ b1,
                       const float* __restrict__ W2,
                       const float* __restrict__ inv_in,
                       const float* __restrict__ inv_out,
                       float* __restrict__ sproj) {
    __shared__ float sW1[WID * WID];
    __shared__ float sb1[WID];
    __shared__ float sW2[WID];
    for (int i = threadIdx.x; i < WID * WID; i += blockDim.x) sW1[i] = W1[i];
    if (threadIdx.x < WID) {
        sb1[threadIdx.x] = b1[threadIdx.x];
        sW2[threadIdx.x] = W2[threadIdx.x];
    }
    __syncthreads();

    int tid = threadIdx.x;
    int sub = tid & (LPN - 1);
    int n = blockIdx.x * NPB + (tid >> LPNSH);   // all n < NNODES (6250*32 exact)

    int start = row_ptr[n];
    int end = (n == NNODES - 1) ? NEDGES : row_ptr[n + 1];

    float acc[WID];
#pragma unroll
    for (int k = 0; k < WID; k++) acc[k] = 0.0f;

    for (int p = start + sub; p < end; p += LPN) {
        float2 c2 = csr[p];
        float w = c2.x;
        int s = __float_as_int(c2.y);
        const __half* hrow = hs + (size_t)s * HHALF;
        uint4 q = *reinterpret_cast<const uint4*>(hrow);
        unsigned int r2 = *reinterpret_cast<const unsigned int*>(hrow + 8);
        float2 f0 = __half22float2(*reinterpret_cast<const __half2*>(&q.x));
        float2 f1 = __half22float2(*reinterpret_cast<const __half2*>(&q.y));
        float2 f2 = __half22float2(*reinterpret_cast<const __half2*>(&q.z));
        float2 f3 = __half22float2(*reinterpret_cast<const __half2*>(&q.w));
        float2 f4 = __half22float2(*reinterpret_cast<const __half2*>(&r2));
        acc[0] += w * f0.x; acc[1] += w * f0.y;
        acc[2] += w * f1.x; acc[3] += w * f1.y;
        acc[4] += w * f2.x; acc[5] += w * f2.y;
        acc[6] += w * f3.x; acc[7] += w * f3.y;
        acc[8] += w * f4.x; acc[9] += w * f4.y;
    }

    // butterfly reduce across the 8-lane group; every lane ends with the sum
#pragma unroll
    for (int m = 1; m < LPN; m <<= 1) {
#pragma unroll
        for (int k = 0; k < WID; k++) acc[k] += __shfl_xor(acc[k], m, 64);
    }

    if (sub != 0) return;
    float ii = inv_in[n];
    float dot = 0.0f;
#pragma unroll
    for (int j = 0; j < WID; j++) {
        float y = 0.0f;
#pragma unroll
        for (int k = 0; k < WID; k++) y += acc[k] * sW1[k * WID + j];
        y = y * ii + sb1[j];
        y = y > 0.0f ? y : 0.0f;
        dot += y * sW2[j];
    }
    sproj[n] = dot * inv_out[n];
}

// ---------------------------------------------------------------------------
// K8: gconv2 aggregate + graph pooling (fence-free).
// __shfl clamps OOR lanes to SELF on AMD -> keep the lane+off<64 guard.
// ---------------------------------------------------------------------------
__global__ void k_agg2_pool(const float2* __restrict__ csr,
                            const int* __restrict__ row_ptr,
                            const float* __restrict__ sproj,
                            const float* __restrict__ inv_in,
                            const float* __restrict__ b2,
                            const int* __restrict__ graph_ids,
                            float* __restrict__ pooled) {
    int tid = threadIdx.x;
    int lane = tid & 63;
    int sub = tid & (LPN - 1);
    int n = blockIdx.x * NPB + (tid >> LPNSH);   // all n < NNODES

    int start = row_ptr[n];
    int end = (n == NNODES - 1) ? NEDGES : row_ptr[n + 1];
    float sum = 0.0f;
    for (int p = start + sub; p < end; p += LPN) {
        float2 c2 = csr[p];
        sum += c2.x * sproj[__float_as_int(c2.y)];
    }
#pragma unroll
    for (int m = 1; m < LPN; m <<= 1) sum += __shfl_xor(sum, m, 64);

    float v = sum * inv_in[n] + b2[0];
    int g = graph_ids[n];

    // segmented suffix-run reduce over the 8 node slots of the wave
#pragma unroll
    for (int off = LPN; off < 64; off <<= 1) {
        float vv = __shfl_down(v, off, 64);
        int gg = __shfl_down(g, off, 64);
        if (lane + off < 64 && gg == g) v += vv;
    }
    int gprev = __shfl_up(g, LPN, 64);
    bool head = (sub == 0) && (lane < LPN || gprev != g);
    if (head) atomicAdd(&pooled[g], v);
}

// ---------------------------------------------------------------------------
// K9: out[g] = pooled[g] / count(g); counts via binary search on sorted gids
// ---------------------------------------------------------------------------
__global__ void k_final(const float* __restrict__ pooled,
                        const int* __restrict__ gids,
                        float* __restrict__ out) {
    int g = blockIdx.x * blockDim.x + threadIdx.x;
    if (g >= NGRAPHS) return;
    int lo = 0, hi = NNODES;
    while (lo < hi) { int m = (lo + hi) >> 1; if (gids[m] < g) lo = m + 1; else hi = m; }
    int first = lo;
    hi = NNODES;
    while (lo < hi) { int m = (lo + hi) >> 1; if (gids[m] < g + 1) lo = m + 1; else hi = m; }
    int cnt = lo - first;
    out[g] = pooled[g] / (float)(cnt > 0 ? cnt : 1);
}

// ---------------------------------------------------------------------------
extern "C" void kernel_launch(void* const* d_in, const int* in_sizes, int n_in,
                              void* d_out, int out_size, void* d_ws, size_t ws_size,
                              hipStream_t stream) {
    const float* atom = (const float*)d_in[0];
    const float* r    = (const float*)d_in[1];
    const float* Wemb = (const float*)d_in[2];
    const float* bemb = (const float*)d_in[3];
    const float* W1   = (const float*)d_in[4];
    const float* b1   = (const float*)d_in[5];
    const float* W2   = (const float*)d_in[6];
    const float* b2   = (const float*)d_in[7];
    const int*   src  = (const int*)d_in[8];
    const int*   dst  = (const int*)d_in[9];
    const int*   gids = (const int*)d_in[10];
    float* out = (float*)d_out;

    // Workspace layout. First regions contiguous, zeroed by ONE memset:
    // pooled | subscan  (subcur filled by scan_top, no zero needed).
    char* w = (char*)d_ws;
    float* pooled  = (float*)w;  w += (size_t)NGRAPHS * 4;          // 2 KB
    int*   subscan = (int*)w;    w += (size_t)NSUBP * 4;            // 6.4 KB
    size_t zbytes = (size_t)NGRAPHS * 4 + (size_t)NSUBP * 4;
    int*   subcur  = (int*)w;    w += (size_t)NSUBP * 4;            // 6.4 KB
    int*   cnt     = (int*)w;    w += (size_t)CNT_N * 4;            // 2.0 MB
    int*   partial = (int*)w;    w += (size_t)((SBLKS + 3) & ~3) * 4;
    int*   row_ptr = (int*)w;    w += (size_t)((NNODES + 4) & ~3) * 4;
    float* inv_in  = (float*)w;  w += (size_t)NNODES * 4;
    float* inv_out = (float*)w;  w += (size_t)NNODES * 4;
    float* sproj   = (float*)w;  w += (size_t)NNODES * 4;
    __half* hs     = (__half*)w; w += (size_t)NNODES * HHALF * 2;   // 6.4 MB
    float2* dstpart = (float2*)w; w += (size_t)NEDGES * 8;          // 51.2 MB
    float2* csrbuf  = (float2*)w; w += (size_t)NEDGES * 8;          // 51.2 MB
    // srcpart aliases csrbuf's first 12.8 MB: consumed by odeg BEFORE
    // k_refine writes dstfine into csrbuf; csr build then sorts IN PLACE.
    unsigned short* srcpart = (unsigned short*)csrbuf;

    hipMemsetAsync(pooled, 0, zbytes, stream);

    const int B = 256;

    k_part_count<<<PBLK, B, 0, stream>>>(src, dst, cnt, subscan);
    k_scan_partial<<<SBLKS, B, 0, stream>>>(cnt, partial);
    k_scan_top<<<1, 1024, 0, stream>>>(partial, subscan, subcur);
    k_scan_apply<<<SBLKS, B, 0, stream>>>(cnt, partial);
    k_part_scatter<<<PBLK, B, 0, stream>>>(r, src, dst, cnt, dstpart, srcpart);
    k_bucket_odeg<<<NB, B, 0, stream>>>(srcpart, cnt, inv_out);   // before refine (alias)
    k_refine<<<REF_GRID, B, 0, stream>>>(dstpart, cnt, subcur, csrbuf);
    k_bucket_csr<<<NSUB, B, 0, stream>>>(csrbuf, subscan, row_ptr, inv_in);
    k_embed<<<NBLK, B, 0, stream>>>(atom, Wemb, bemb, inv_out, hs);
    k_agg1<<<AGG_BLKS, B, 0, stream>>>(csrbuf, row_ptr, hs, W1, b1, W2, inv_in, inv_out, sproj);
    k_agg2_pool<<<AGG_BLKS, B, 0, stream>>>(csrbuf, row_ptr, sproj, inv_in, b2, gids, pooled);
    k_final<<<(NGRAPHS + B - 1) / B, B, 0, stream>>>(pooled, gids, out);
}

// Round 12
// 610.299 us; speedup vs baseline: 1.8509x; 1.0450x over previous
//
#include <hip/hip_runtime.h>
#include <hip/hip_fp16.h>
#include <math.h>

#define NNODES  200000
#define NEDGES  6400000
#define NGRAPHS 512
#define FIN     92
#define WID     10
#define HHALF   16                     // hs row = 10 fp16 padded to 16 (32 B)
#define NBLK    ((NNODES + 255) / 256) // 782

// partition geometry (round-12 proven config; fp16 hs since round-11).
// Round-12 change: scatter REGISTER-STAGED (pass B re-read of src/dst/r
// eliminated -- 25 L2-latency loads/thread/tile were the stall source at
// 46% occupancy / 10% VALU / 1.9 TB/s); odeg widened to 512 threads.
#define LBITS   10
#define LSIZE   1024                   // coarse bucket (both planes)
#define LMASK   (LSIZE - 1)
#define NB      196                    // coarse buckets
#define SUBSH   7
#define SUBN    128                    // dst nodes per sub-bucket
#define NSUB    1563                   // ceil(200000/128) dst sub-buckets
#define NSUBP   1608                   // padded alloc (incl sentinel)
#define PBLK    1280                   // partition blocks (5/CU exact)
#define EPB     (NEDGES / PBLK)        // 5000 edges per partition block (exact)
#define TILE    1250                   // staging tile (EPB = 4 * TILE exactly)
#define NTILE   (EPB / TILE)           // 4
#define EPT     5                      // max edges per thread per tile
#define CELLS   (2 * NB)               // 392 (dst plane + src plane)
#define CNT_N   (CELLS * PBLK)         // 501,760 scan elements
#define SBLKS   (CNT_N / 256)          // 1960 scan blocks (exact)
#define REF_GRID (NB * 8)              // 1568 refine blocks (8 per parent)

// chunk-ordered rows (kept: csr sorted by (local, srcChunk))
#define CHBITS  14
#define NCHK    13                     // ceil(200000/16384) src chunks
#define SKEYS   (SUBN * NCHK)          // 1664 keys per sub-bucket
#define SKPAD   1792                   // 256*7 padded key array
#define SKPT    7                      // keys per thread in scan
#define SMAX    5120                   // LDS staging cap: mean 4096 + 16 sigma

// agg: 8 lanes/node, ONE counted loop, ZERO barriers.
// Journal: no __threadfence on per-block paths (r8); no per-element
// device atomics (r9); no global phase locks (r7).
#define LPN     8
#define LPNSH   3
#define NPB     (256 / LPN)            // 32 nodes per block
#define AGG_BLKS (NNODES / NPB)        // 6250 (exact)

// ---------------------------------------------------------------------------
// P1: per-(bucket,block) counts via LDS histograms; dst at sub-bucket
// granularity summed 8-way (coarse cnt) + totals into subcnt; src at
// coarse granularity into the cnt src plane. ZERO global hot-path atomics.
// ---------------------------------------------------------------------------
__global__ void k_part_count(const int* __restrict__ src,
                             const int* __restrict__ dst,
                             int* __restrict__ cnt,
                             int* __restrict__ subcnt) {
    __shared__ int hSub[NSUB];
    __shared__ int hS[NB];
    int tid = threadIdx.x, k = blockIdx.x;
    for (int i = tid; i < NSUB; i += 256) hSub[i] = 0;
    if (tid < NB) hS[tid] = 0;
    __syncthreads();
    int base = k * EPB;
    for (int i = tid; i < EPB; i += 256) {
        int e = base + i;
        atomicAdd(&hSub[dst[e] >> SUBSH], 1);
        atomicAdd(&hS[src[e] >> LBITS], 1);
    }
    __syncthreads();
    if (tid < NB) {
        int s = 0;
        int b0 = tid * 8;
#pragma unroll
        for (int j = 0; j < 8; j++) {
            int ix = b0 + j;
            if (ix < NSUB) s += hSub[ix];
        }
        cnt[tid * PBLK + k] = s;
        cnt[(NB + tid) * PBLK + k] = hS[tid];
    }
    for (int i = tid; i < NSUB; i += 256) {
        int v = hSub[i];
        if (v) atomicAdd(&subcnt[i], v);
    }
}

// ---------------------------------------------------------------------------
// Scan step 1: per-block (256-elem) partial sums of cnt
// ---------------------------------------------------------------------------
__global__ void k_scan_partial(const int* __restrict__ cnt,
                               int* __restrict__ partial) {
    __shared__ int sdata[256];
    int tid = threadIdx.x;
    sdata[tid] = cnt[blockIdx.x * 256 + tid];
    __syncthreads();
    for (int s = 128; s > 0; s >>= 1) {
        if (tid < s) sdata[tid] += sdata[tid + s];
        __syncthreads();
    }
    if (tid == 0) partial[blockIdx.x] = sdata[0];
}

// ---------------------------------------------------------------------------
// Scan step 2: single-block exclusive scan of the 1960 partials, FUSED with
// the sub-bucket scan (2 cells/thread; 2048 >= 1563).
// ---------------------------------------------------------------------------
__global__ void k_scan_top(int* __restrict__ partial,
                           int* __restrict__ subcnt,
                           int* __restrict__ subcur) {
    __shared__ int buf[1024];
    __shared__ int carry_s;
    int tid = threadIdx.x;
    if (tid == 0) carry_s = 0;
    __syncthreads();
    for (int base = 0; base < SBLKS; base += 1024) {
        int i = base + tid;
        int c = carry_s;
        int orig = (i < SBLKS) ? partial[i] : 0;
        buf[tid] = orig;
        __syncthreads();
        for (int off = 1; off < 1024; off <<= 1) {
            int t = (tid >= off) ? buf[tid - off] : 0;
            __syncthreads();
            buf[tid] += t;
            __syncthreads();
        }
        if (i < SBLKS) partial[i] = buf[tid] - orig + c;
        __syncthreads();
        if (tid == 0) carry_s = c + buf[1023];
        __syncthreads();
    }
    // ---- fused subscan: exclusive scan of 1563 sub-bucket counts ----
    int c0 = tid * 2, c1 = tid * 2 + 1;
    int v0 = (c0 < NSUB) ? subcnt[c0] : 0;
    int v1 = (c1 < NSUB) ? subcnt[c1] : 0;
    int sum = v0 + v1;
    buf[tid] = sum;
    __syncthreads();
    for (int off = 1; off < 1024; off <<= 1) {
        int t = (tid >= off) ? buf[tid - off] : 0;
        __syncthreads();
        buf[tid] += t;
        __syncthreads();
    }
    int run = buf[tid] - sum;
    if (c0 < NSUB) { subcnt[c0] = run; subcur[c0] = run; run += v0; }
    if (c1 < NSUB) { subcnt[c1] = run; subcur[c1] = run; }
    if (tid == 0) subcnt[NSUB] = NEDGES;
}

// ---------------------------------------------------------------------------
// Scan step 3: apply -- in-place exclusive scan of cnt
// ---------------------------------------------------------------------------
__global__ void k_scan_apply(int* __restrict__ cnt,
                             const int* __restrict__ partial) {
    __shared__ int buf[256];
    int tid = threadIdx.x;
    int i = blockIdx.x * 256 + tid;
    int v = cnt[i];
    buf[tid] = v;
    __syncthreads();
    for (int off = 1; off < 256; off <<= 1) {
        int t = (tid >= off) ? buf[tid - off] : 0;
        __syncthreads();
        buf[tid] += t;
        __syncthreads();
    }
    cnt[i] = buf[tid] - v + partial[blockIdx.x];
}

// ---------------------------------------------------------------------------
// P2: TILE-STAGED coarse scatter, round-12 REGISTER-STAGED version.
// Per tile: ONE read of src/dst/r into registers (keys, weights, packed
// cells) -> hist from regs -> two 2-barrier shfl wave-scans -> place from
// regs into SoA staging -> coalesced copy-out. ZERO global atomics; zero
// second-pass global reads.
// ---------------------------------------------------------------------------
__global__ void k_part_scatter(const float* __restrict__ r,
                               const int* __restrict__ src,
                               const int* __restrict__ dst,
                               const int* __restrict__ cnt,
                               float2* __restrict__ dstpart,
                               unsigned short* __restrict__ srcpart) {
    __shared__ int curD[NB], curS[NB];     // running global cursors
    __shared__ int hD[NB], hS[NB];         // tile hist, then tile cursor
    __shared__ int baseD[NB], baseS[NB];   // tile-local exclusive base
    __shared__ int segD[NB], segS[NB];     // global cursor snapshot at tile start
    __shared__ int wsum[4];                // cross-wave scan fixup
    __shared__ float stW[TILE];            //  5 KB staged weights
    __shared__ int   stK[TILE];            //  5 KB staged keys
    __shared__ int   ddD[TILE];            //  5 KB their global slots
    __shared__ unsigned short stS[TILE];   //2.5 KB staged src locals
    __shared__ int   ddS[TILE];            //  5 KB their global slots

    int tid = threadIdx.x, k = blockIdx.x;
    int lane = tid & 63, wv = tid >> 6;
    if (tid < NB) {
        curD[tid] = cnt[tid * PBLK + k];
        curS[tid] = cnt[(NB + tid) * PBLK + k] - NEDGES;
    }
    __syncthreads();

    const float3* r3 = reinterpret_cast<const float3*>(r);
    int base = k * EPB;
    for (int t = 0; t < NTILE; t++) {
        int tbase = base + t * TILE;

        // ---- load phase: each thread stages its <=5 edges in registers ----
        float ws[EPT];
        int   keys[EPT];   // (s<<10) | (d & 1023)
        int   cells[EPT];  // (d>>10)<<8 | (s>>10)
#pragma unroll
        for (int j = 0; j < EPT; j++) {
            int i = tid + j * 256;
            if (i < TILE) {
                int e = tbase + i;
                int s = src[e], d = dst[e];
                float3 rv = r3[e];
                ws[j] = expf(-(rv.x * rv.x + rv.y * rv.y + rv.z * rv.z));
                keys[j] = (s << LBITS) | (d & LMASK);
                cells[j] = ((d >> LBITS) << 8) | (s >> LBITS);
            } else {
                keys[j] = -1;
            }
        }

        if (tid < NB) { hD[tid] = 0; hS[tid] = 0; }
        __syncthreads();
        // pass A: tile histograms from registers
#pragma unroll
        for (int j = 0; j < EPT; j++) {
            if (keys[j] != -1) {
                atomicAdd(&hD[cells[j] >> 8], 1);
                atomicAdd(&hS[cells[j] & 255], 1);
            }
        }
        __syncthreads();
        // --- scan dst plane: 6-step shfl wave scan + 4-partial fixup ---
        {
            int v = (tid < NB) ? hD[tid] : 0;
            int x = v;
#pragma unroll
            for (int off = 1; off < 64; off <<= 1) {
                int tv = __shfl_up(x, off, 64);
                if (lane >= off) x += tv;
            }
            if (lane == 63) wsum[wv] = x;
            __syncthreads();
            if (tid == 0) {
                int a = 0;
#pragma unroll
                for (int wvi = 0; wvi < 4; wvi++) { int tv = wsum[wvi]; wsum[wvi] = a; a += tv; }
            }
            __syncthreads();
            int excl = x - v + wsum[wv];
            if (tid < NB) {
                baseD[tid] = excl;
                segD[tid] = curD[tid];
                curD[tid] += v;
                hD[tid] = excl;        // reuse as tile cursor
            }
        }
        __syncthreads();
        // --- scan src plane ---
        {
            int v = (tid < NB) ? hS[tid] : 0;
            int x = v;
#pragma unroll
            for (int off = 1; off < 64; off <<= 1) {
                int tv = __shfl_up(x, off, 64);
                if (lane >= off) x += tv;
            }
            if (lane == 63) wsum[wv] = x;
            __syncthreads();
            if (tid == 0) {
                int a = 0;
#pragma unroll
                for (int wvi = 0; wvi < 4; wvi++) { int tv = wsum[wvi]; wsum[wvi] = a; a += tv; }
            }
            __syncthreads();
            int excl = x - v + wsum[wv];
            if (tid < NB) {
                baseS[tid] = excl;
                segS[tid] = curS[tid];
                curS[tid] += v;
                hS[tid] = excl;
            }
        }
        __syncthreads();
        // pass B: place from registers, precompute global destinations
#pragma unroll
        for (int j = 0; j < EPT; j++) {
            if (keys[j] != -1) {
                int cd = cells[j] >> 8;
                int idx = atomicAdd(&hD[cd], 1);
                stW[idx] = ws[j];
                stK[idx] = keys[j];
                ddD[idx] = segD[cd] + (idx - baseD[cd]);
                int cs = cells[j] & 255;
                int ids = atomicAdd(&hS[cs], 1);
                stS[ids] = (unsigned short)((unsigned)keys[j] >> LBITS) & LMASK;
                ddS[ids] = segS[cs] + (ids - baseS[cs]);
            }
        }
        __syncthreads();
        // pass C: coalesced copy-out
        for (int i = tid; i < TILE; i += 256) {
            dstpart[ddD[i]] = make_float2(stW[i], __int_as_float(stK[i]));
            srcpart[ddS[i]] = stS[i];
        }
        __syncthreads();
    }
}

// ---------------------------------------------------------------------------
// P3s: per-bucket out-degree histogram (LDS) -> inv_sqrt_out.
// Round-12: 512 threads (was 256) -- the kernel is grid-starved at 196
// blocks; halving the per-thread serial chain halves the latency exposure.
// Runs BEFORE k_refine because srcpart aliases the csr/dstfine region.
// ---------------------------------------------------------------------------
__global__ void k_bucket_odeg(const unsigned short* __restrict__ srcpart,
                              const int* __restrict__ cnt,
                              float* __restrict__ inv_out) {
    __shared__ int hist[LSIZE];
    int tid = threadIdx.x, b = blockIdx.x;
    int bstart = cnt[(NB + b) * PBLK] - NEDGES;
    int bend = (b == NB - 1) ? NEDGES : (cnt[(NB + b + 1) * PBLK] - NEDGES);
    for (int l = tid; l < LSIZE; l += 512) hist[l] = 0;
    __syncthreads();
    for (int p = bstart + tid; p < bend; p += 512)
        atomicAdd(&hist[srcpart[p]], 1);
    __syncthreads();
    for (int l = tid; l < LSIZE; l += 512) {
        int n = (b << LBITS) + l;
        if (n < NNODES) {
            int c = hist[l];
            inv_out[n] = rsqrtf((float)(c < 1 ? 1 : c));
        }
    }
}

// ---------------------------------------------------------------------------
// 8-way refine, coarse bucket -> 128-node sub-buckets (round-4-proven).
// ---------------------------------------------------------------------------
__global__ void k_refine(const float2* __restrict__ dstpart,
                         const int* __restrict__ cnt,
                         int* __restrict__ subcur,
                         float2* __restrict__ dstfine) {
    int p = blockIdx.x >> 3;          // parent bucket
    int q = blockIdx.x & 7;           // eighth of its range
    int bstart = cnt[p * PBLK];
    int bend = (p == NB - 1) ? NEDGES : cnt[(p + 1) * PBLK];
    int sz = bend - bstart;
    int qs = bstart + (int)(((long long)sz * q) >> 3);
    int qe = bstart + (int)(((long long)sz * (q + 1)) >> 3);
    int lane = threadIdx.x & 63;
    int wv = threadIdx.x >> 6;        // 4 waves per block

    for (int base = qs + wv * 64; base < qe; base += 256) {
        int i = base + lane;
        bool act = (i < qe);
        float2 rec = make_float2(0.0f, 0.0f);
        if (act) rec = dstpart[i];
        unsigned pk = __float_as_uint(rec.y);
        int s3 = (pk >> SUBSH) & 7;   // sub index within parent
        unsigned long long b0 = __ballot(s3 & 1);
        unsigned long long b1 = __ballot(s3 & 2);
        unsigned long long b2 = __ballot(s3 & 4);
        unsigned long long am = __ballot(act);
        unsigned long long M = ((s3 & 1) ? b0 : ~b0)
                             & ((s3 & 2) ? b1 : ~b1)
                             & ((s3 & 4) ? b2 : ~b2) & am;
        if (act) {
            int cj = __popcll(M);
            int rank = __popcll(M & ((1ull << lane) - 1ull));
            int leader = __ffsll((unsigned long long)M) - 1;
            int gb = 0;
            if (lane == leader) gb = atomicAdd(&subcur[p * 8 + s3], cj);
            gb = __shfl(gb, leader, 64);
            dstfine[gb + rank] = rec;
        }
    }
}

// ---------------------------------------------------------------------------
// P3d: per-sub-bucket CSR build (round-3-proven), IN PLACE.
// ---------------------------------------------------------------------------
__global__ void k_bucket_csr(float2* __restrict__ data,
                             const int* __restrict__ subscan,
                             int* __restrict__ row_ptr,
                             float* __restrict__ inv_in) {
    __shared__ int hist[SKPAD];      //  7,168 B
    __shared__ int sbuf[256];        //  1,024 B
    __shared__ float2 stout[SMAX];   // 40,960 B
    int tid = threadIdx.x;
    int sub = blockIdx.x;
    int substart = subscan[sub];
    int subend = subscan[sub + 1];
    int sz = subend - substart;

    for (int j = tid; j < SKPAD; j += 256) hist[j] = 0;
    __syncthreads();
    // count keys over own range only
    for (int p = substart + tid; p < subend; p += 256) {
        unsigned pk = __float_as_uint(data[p].y);
        atomicAdd(&hist[(pk & 127u) * NCHK + (pk >> 24)], 1);
    }
    __syncthreads();
    // exclusive scan over the 1792 (padded) keys
    int kb = tid * SKPT;
    int sum = 0;
#pragma unroll
    for (int j = 0; j < SKPT; j++) sum += hist[kb + j];
    sbuf[tid] = sum;
    __syncthreads();
    for (int off = 1; off < 256; off <<= 1) {
        int tv = (tid >= off) ? sbuf[tid - off] : 0;
        __syncthreads();
        sbuf[tid] += tv;
        __syncthreads();
    }
    int run = sbuf[tid] - sum + substart;   // global cursor for own keys
#pragma unroll
    for (int j = 0; j < SKPT; j++) {
        int c = hist[kb + j];
        hist[kb + j] = run;
        run += c;
    }
    __syncthreads();
    // rows: start = cursor at key l*NCHK (read BEFORE placement mutates)
    if (tid < SUBN) {
        int l = tid;
        int rs = hist[l * NCHK];
        int re = (l == SUBN - 1) ? subend : hist[(l + 1) * NCHK];
        int n = (sub << SUBSH) + l;
        if (n < NNODES) {
            row_ptr[n] = rs;
            int c = re - rs;
            inv_in[n] = rsqrtf((float)(c < 1 ? 1 : c));
        }
    }
    __syncthreads();
    // placement into LDS staging (reads own range only; no global writes yet)
    if (sz <= SMAX) {
        for (int p = substart + tid; p < subend; p += 256) {
            float2 rec = data[p];
            unsigned pk = __float_as_uint(rec.y);
            int pos = atomicAdd(&hist[(pk & 127u) * NCHK + (pk >> 24)], 1);
            stout[pos - substart] = make_float2(rec.x, __int_as_float((int)(pk >> LBITS)));
        }
        __syncthreads();
        // coalesced copy-out (all reads of own range completed above)
        for (int i = tid; i < sz; i += 256)
            data[substart + i] = stout[i];
    } else {
        // overflow fallback (statistically unreachable: SMAX = mean + 16 sigma)
        for (int p = substart + tid; p < subend; p += 256) {
            float2 rec = data[p];
            unsigned pk = __float_as_uint(rec.y);
            int pos = atomicAdd(&hist[(pk & 127u) * NCHK + (pk >> 24)], 1);
            data[pos] = make_float2(rec.x, __int_as_float((int)(pk >> LBITS)));
        }
    }
}

// ---------------------------------------------------------------------------
// K5: hs[n,:] = fp16( (A[n,:] @ W_emb + b_emb) * inv_sqrt_out[n] ).
// Rows are 10 fp16 padded to 16 (32 B stride); written as uint4 + uint.
// ---------------------------------------------------------------------------
__global__ void k_embed(const float* __restrict__ A,
                        const float* __restrict__ Wemb,
                        const float* __restrict__ bemb,
                        const float* __restrict__ inv_out,
                        __half* __restrict__ hs) {
    __shared__ float sW[FIN * WID];
    __shared__ float sb[WID];
    for (int i = threadIdx.x; i < FIN * WID; i += blockDim.x) sW[i] = Wemb[i];
    if (threadIdx.x < WID) sb[threadIdx.x] = bemb[threadIdx.x];
    __syncthreads();

    int n = blockIdx.x * blockDim.x + threadIdx.x;
    if (n >= NNODES) return;

    float acc[WID];
#pragma unroll
    for (int k = 0; k < WID; k++) acc[k] = sb[k];

    const float4* row4 = reinterpret_cast<const float4*>(A + (size_t)n * FIN);
#pragma unroll
    for (int f4 = 0; f4 < FIN / 4; f4++) {
        float4 v = row4[f4];
        int f = f4 * 4;
#pragma unroll
        for (int k = 0; k < WID; k++) acc[k] += v.x * sW[(f + 0) * WID + k];
#pragma unroll
        for (int k = 0; k < WID; k++) acc[k] += v.y * sW[(f + 1) * WID + k];
#pragma unroll
        for (int k = 0; k < WID; k++) acc[k] += v.z * sW[(f + 2) * WID + k];
#pragma unroll
        for (int k = 0; k < WID; k++) acc[k] += v.w * sW[(f + 3) * WID + k];
    }

    float sc = inv_out[n];
    __half2 hp[5];
#pragma unroll
    for (int k2 = 0; k2 < 5; k2++)
        hp[k2] = __float22half2_rn(make_float2(acc[2 * k2] * sc, acc[2 * k2 + 1] * sc));
    unsigned int* hpu = reinterpret_cast<unsigned int*>(hp);
    __half* outp = hs + (size_t)n * HHALF;
    *reinterpret_cast<uint4*>(outp) = make_uint4(hpu[0], hpu[1], hpu[2], hpu[3]);
    *reinterpret_cast<unsigned int*>(outp + 8) = hpu[4];
}

// ---------------------------------------------------------------------------
// K7: 8 lanes/node, ONE counted loop, no barriers. hs rows are fp16 (32 B):
// 2 loads/edge (uint4 + uint), 5x half2->float2 convert.
// Butterfly reduce + fused 10x10 + gconv2 projection.
// ---------------------------------------------------------------------------
__global__ void k_agg1(const float2* __restrict__ csr,
                       const int* __restrict__ row_ptr,
                       const __half* __restrict__ hs,
                       const float* __restrict__ W1,
                       const float* __restrict__ b1,
                       const float* __restrict__ W2,
                       const float* __restrict__ inv_in,
                       const float* __restrict__ inv_out,
                       float* __restrict__ sproj) {
    __shared__ float sW1[WID * WID];
    __shared__ float sb1[WID];
    __shared__ float sW2[WID];
    for (int i = threadIdx.x; i < WID * WID; i += blockDim.x) sW1[i] = W1[i];
    if (threadIdx.x < WID) {
        sb1[threadIdx.x] = b1[threadIdx.x];
        sW2[threadIdx.x] = W2[threadIdx.x];
    }
    __syncthreads();

    int tid = threadIdx.x;
    int sub = tid & (LPN - 1);
    int n = blockIdx.x * NPB + (tid >> LPNSH);   // all n < NNODES (6250*32 exact)

    int start = row_ptr[n];
    int end = (n == NNODES - 1) ? NEDGES : row_ptr[n + 1];

    float acc[WID];
#pragma unroll
    for (int k = 0; k < WID; k++) acc[k] = 0.0f;

    for (int p = start + sub; p < end; p += LPN) {
        float2 c2 = csr[p];
        float w = c2.x;
        int s = __float_as_int(c2.y);
        const __half* hrow = hs + (size_t)s * HHALF;
        uint4 q = *reinterpret_cast<const uint4*>(hrow);
        unsigned int r2 = *reinterpret_cast<const unsigned int*>(hrow + 8);
        float2 f0 = __half22float2(*reinterpret_cast<const __half2*>(&q.x));
        float2 f1 = __half22float2(*reinterpret_cast<const __half2*>(&q.y));
        float2 f2 = __half22float2(*reinterpret_cast<const __half2*>(&q.z));
        float2 f3 = __half22float2(*reinterpret_cast<const __half2*>(&q.w));
        float2 f4 = __half22float2(*reinterpret_cast<const __half2*>(&r2));
        acc[0] += w * f0.x; acc[1] += w * f0.y;
        acc[2] += w * f1.x; acc[3] += w * f1.y;
        acc[4] += w * f2.x; acc[5] += w * f2.y;
        acc[6] += w * f3.x; acc[7] += w * f3.y;
        acc[8] += w * f4.x; acc[9] += w * f4.y;
    }

    // butterfly reduce across the 8-lane group; every lane ends with the sum
#pragma unroll
    for (int m = 1; m < LPN; m <<= 1) {
#pragma unroll
        for (int k = 0; k < WID; k++) acc[k] += __shfl_xor(acc[k], m, 64);
    }

    if (sub != 0) return;
    float ii = inv_in[n];
    float dot = 0.0f;
#pragma unroll
    for (int j = 0; j < WID; j++) {
        float y = 0.0f;
#pragma unroll
        for (int k = 0; k < WID; k++) y += acc[k] * sW1[k * WID + j];
        y = y * ii + sb1[j];
        y = y > 0.0f ? y : 0.0f;
        dot += y * sW2[j];
    }
    sproj[n] = dot * inv_out[n];
}

// ---------------------------------------------------------------------------
// K8: gconv2 aggregate + graph pooling (fence-free).
// __shfl clamps OOR lanes to SELF on AMD -> keep the lane+off<64 guard.
// ---------------------------------------------------------------------------
__global__ void k_agg2_pool(const float2* __restrict__ csr,
                            const int* __restrict__ row_ptr,
                            const float* __restrict__ sproj,
                            const float* __restrict__ inv_in,
                            const float* __restrict__ b2,
                            const int* __restrict__ graph_ids,
                            float* __restrict__ pooled) {
    int tid = threadIdx.x;
    int lane = tid & 63;
    int sub = tid & (LPN - 1);
    int n = blockIdx.x * NPB + (tid >> LPNSH);   // all n < NNODES

    int start = row_ptr[n];
    int end = (n == NNODES - 1) ? NEDGES : row_ptr[n + 1];
    float sum = 0.0f;
    for (int p = start + sub; p < end; p += LPN) {
        float2 c2 = csr[p];
        sum += c2.x * sproj[__float_as_int(c2.y)];
    }
#pragma unroll
    for (int m = 1; m < LPN; m <<= 1) sum += __shfl_xor(sum, m, 64);

    float v = sum * inv_in[n] + b2[0];
    int g = graph_ids[n];

    // segmented suffix-run reduce over the 8 node slots of the wave
#pragma unroll
    for (int off = LPN; off < 64; off <<= 1) {
        float vv = __shfl_down(v, off, 64);
        int gg = __shfl_down(g, off, 64);
        if (lane + off < 64 && gg == g) v += vv;
    }
    int gprev = __shfl_up(g, LPN, 64);
    bool head = (sub == 0) && (lane < LPN || gprev != g);
    if (head) atomicAdd(&pooled[g], v);
}

// ---------------------------------------------------------------------------
// K9: out[g] = pooled[g] / count(g); counts via binary search on sorted gids
// ---------------------------------------------------------------------------
__global__ void k_final(const float* __restrict__ pooled,
                        const int* __restrict__ gids,
                        float* __restrict__ out) {
    int g = blockIdx.x * blockDim.x + threadIdx.x;
    if (g >= NGRAPHS) return;
    int lo = 0, hi = NNODES;
    while (lo < hi) { int m = (lo + hi) >> 1; if (gids[m] < g) lo = m + 1; else hi = m; }
    int first = lo;
    hi = NNODES;
    while (lo < hi) { int m = (lo + hi) >> 1; if (gids[m] < g + 1) lo = m + 1; else hi = m; }
    int cnt = lo - first;
    out[g] = pooled[g] / (float)(cnt > 0 ? cnt : 1);
}

// ---------------------------------------------------------------------------
extern "C" void kernel_launch(void* const* d_in, const int* in_sizes, int n_in,
                              void* d_out, int out_size, void* d_ws, size_t ws_size,
                              hipStream_t stream) {
    const float* atom = (const float*)d_in[0];
    const float* r    = (const float*)d_in[1];
    const float* Wemb = (const float*)d_in[2];
    const float* bemb = (const float*)d_in[3];
    const float* W1   = (const float*)d_in[4];
    const float* b1   = (const float*)d_in[5];
    const float* W2   = (const float*)d_in[6];
    const float* b2   = (const float*)d_in[7];
    const int*   src  = (const int*)d_in[8];
    const int*   dst  = (const int*)d_in[9];
    const int*   gids = (const int*)d_in[10];
    float* out = (float*)d_out;

    // Workspace layout. First regions contiguous, zeroed by ONE memset:
    // pooled | subscan  (subcur filled by scan_top, no zero needed).
    char* w = (char*)d_ws;
    float* pooled  = (float*)w;  w += (size_t)NGRAPHS * 4;          // 2 KB
    int*   subscan = (int*)w;    w += (size_t)NSUBP * 4;            // 6.4 KB
    size_t zbytes = (size_t)NGRAPHS * 4 + (size_t)NSUBP * 4;
    int*   subcur  = (int*)w;    w += (size_t)NSUBP * 4;            // 6.4 KB
    int*   cnt     = (int*)w;    w += (size_t)CNT_N * 4;            // 2.0 MB
    int*   partial = (int*)w;    w += (size_t)((SBLKS + 3) & ~3) * 4;
    int*   row_ptr = (int*)w;    w += (size_t)((NNODES + 4) & ~3) * 4;
    float* inv_in  = (float*)w;  w += (size_t)NNODES * 4;
    float* inv_out = (float*)w;  w += (size_t)NNODES * 4;
    float* sproj   = (float*)w;  w += (size_t)NNODES * 4;
    __half* hs     = (__half*)w; w += (size_t)NNODES * HHALF * 2;   // 6.4 MB
    float2* dstpart = (float2*)w; w += (size_t)NEDGES * 8;          // 51.2 MB
    float2* csrbuf  = (float2*)w; w += (size_t)NEDGES * 8;          // 51.2 MB
    // srcpart aliases csrbuf's first 12.8 MB: consumed by odeg BEFORE
    // k_refine writes dstfine into csrbuf; csr build then sorts IN PLACE.
    unsigned short* srcpart = (unsigned short*)csrbuf;

    hipMemsetAsync(pooled, 0, zbytes, stream);

    const int B = 256;

    k_part_count<<<PBLK, B, 0, stream>>>(src, dst, cnt, subscan);
    k_scan_partial<<<SBLKS, B, 0, stream>>>(cnt, partial);
    k_scan_top<<<1, 1024, 0, stream>>>(partial, subscan, subcur);
    k_scan_apply<<<SBLKS, B, 0, stream>>>(cnt, partial);
    k_part_scatter<<<PBLK, B, 0, stream>>>(r, src, dst, cnt, dstpart, srcpart);
    k_bucket_odeg<<<NB, 512, 0, stream>>>(srcpart, cnt, inv_out);   // before refine (alias)
    k_refine<<<REF_GRID, B, 0, stream>>>(dstpart, cnt, subcur, csrbuf);
    k_bucket_csr<<<NSUB, B, 0, stream>>>(csrbuf, subscan, row_ptr, inv_in);
    k_embed<<<NBLK, B, 0, stream>>>(atom, Wemb, bemb, inv_out, hs);
    k_agg1<<<AGG_BLKS, B, 0, stream>>>(csrbuf, row_ptr, hs, W1, b1, W2, inv_in, inv_out, sproj);
    k_agg2_pool<<<AGG_BLKS, B, 0, stream>>>(csrbuf, row_ptr, sproj, inv_in, b2, gids, pooled);
    k_final<<<(NGRAPHS + B - 1) / B, B, 0, stream>>>(pooled, gids, out);
}